// Round 17
// baseline (581.003 us; speedup 1.0000x reference)
//
#include <hip/hip_runtime.h>
#include <hip/hip_bf16.h>

typedef __attribute__((ext_vector_type(8))) short short8;
typedef __attribute__((ext_vector_type(4))) float floatx4;

#define NB 128      // batch N
#define LS 64       // seq L
#define HD 512      // hidden H
#define ED 512      // embed E
#define NH 65536    // NB*HD elements per s-slab
#define LDA 72      // LDS tile stride for reg-staged kernels (64 + 8 pad)
#define LDC 136     // LDS C-tile stride bf16 (128 + 8 pad)
#define LDCF 132    // LDS C-tile stride f32 (128 + 4 pad)

// ws layout (byte offsets)
#define OFF_WIN    0ull          // W_in bf16   [512*512]
#define OFF_WOUT   524288ull     // W_out bf16  [512*512]
#define OFF_XT     1048576ull    // x_t bf16    [64][128][512]  (= level 0)
#define OFF_LVL0   9437184ull    // level ping  bf16 [64][128][512]
#define OFF_LVL1   17825792ull   // level pong  bf16 [64][128][512]
#define OFF_OUTS   26214400ull   // outs bf16   [64][128][512]
#define OFF_PHA    34603008ull   // P hi ping  bf16 (5x 512x512, 2.62 MB)
#define OFF_PLA    37224448ull   // P lo ping
#define OFF_PHB    39845888ull   // P hi pong
#define OFF_PLB    42467328ull   // P lo pong
#define OFF_BCAT   45088768ull   // Bcat_1..4 bf16 concat (7 MB); Bcat_1 == WsHi
#define OFF_BETA   52428800ull   // beta_1..4 f32 [4][512]
#define OFF_PART   52436992ull   // partials f32 [128]
#define OFF_WSLO   52437504ull   // W_sani lo bf16 [512*1024] (1 MB)
#define OFF_Y      OFF_LVL0      // Y f32 [8192][512] aliases lvl bufs after recurrence

static __device__ __forceinline__ unsigned short f2b(float f) {
  unsigned u = __float_as_uint(f);
  u += 0x7fffu + ((u >> 16) & 1u);   // round-to-nearest-even
  return (unsigned short)(u >> 16);
}
static __device__ __forceinline__ float b2f(unsigned short h) {
  return __uint_as_float(((unsigned)h) << 16);
}

// async global -> LDS, 16B per lane; LDS dest = wave-uniform base + lane*16
static __device__ __forceinline__ void gl_lds16(const unsigned short* g, unsigned short* l) {
  __builtin_amdgcn_global_load_lds(
      (const __attribute__((address_space(1))) void*)g,
      (__attribute__((address_space(3))) void*)l, 16, 0, 0);
}

// load 8 consecutive f32, produce bf16x8 packed (hi only; used for emb gather)
static __device__ __forceinline__ uint4 cvt8hi(const float* s) {
  floatx4 f0 = *(const floatx4*)s;
  floatx4 f1 = *(const floatx4*)(s + 4);
  float f[8] = {f0.x, f0.y, f0.z, f0.w, f1.x, f1.y, f1.z, f1.w};
  unsigned short b[8];
#pragma unroll
  for (int k = 0; k < 8; ++k) b[k] = f2b(f[k]);
  uint4 u;
  u.x = b[0] | ((unsigned)b[1] << 16); u.y = b[2] | ((unsigned)b[3] << 16);
  u.z = b[4] | ((unsigned)b[5] << 16); u.w = b[6] | ((unsigned)b[7] << 16);
  return u;
}

// ---- padded-LDS GEMM core (emb branch): BM=64, BN=128, 4 waves 2x2 ----
__device__ __forceinline__ void gemm_core24(const unsigned short* As, const unsigned short* Bs,
                                            floatx4 acc[2][4], int wm, int wn, int lane) {
  const int rb = lane & 15;
  const int kg = (lane >> 4) * 8;
#pragma unroll
  for (int kk = 0; kk < 64; kk += 32) {
    short8 a[2], b[4];
#pragma unroll
    for (int i = 0; i < 2; ++i)
      a[i] = *(const short8*)&As[(wm * 32 + i * 16 + rb) * LDA + kk + kg];
#pragma unroll
    for (int j = 0; j < 4; ++j)
      b[j] = *(const short8*)&Bs[(wn * 64 + j * 16 + rb) * LDA + kk + kg];
#pragma unroll
    for (int i = 0; i < 2; ++i)
#pragma unroll
      for (int j = 0; j < 4; ++j)
        acc[i][j] = __builtin_amdgcn_mfma_f32_16x16x32_bf16(a[i], b[j], acc[i][j], 0, 0, 0);
  }
}

// ---- UNPADDED stride-64 core with XOR bank swizzle (64-row tiles). ----
__device__ __forceinline__ void gemm_core64s(const unsigned short* As, const unsigned short* Bs,
                                             floatx4 acc[2][4], int wm, int wn, int lane) {
  const int rb = lane & 15;
  const int kg = (lane >> 4) * 8;
  const int xv = (rb & 7) * 8;       // XOR swizzle, units of 8 shorts (16B)
#pragma unroll
  for (int kk = 0; kk < 64; kk += 32) {
    const int co = (kk + kg) ^ xv;   // kk+kg is a multiple of 8 -> pure slot XOR
    short8 a[2], b[4];
#pragma unroll
    for (int i = 0; i < 2; ++i)
      a[i] = *(const short8*)&As[(wm * 32 + i * 16 + rb) * 64 + co];
#pragma unroll
    for (int j = 0; j < 4; ++j)
      b[j] = *(const short8*)&Bs[(wn * 64 + j * 16 + rb) * 64 + co];
#pragma unroll
    for (int i = 0; i < 2; ++i)
#pragma unroll
      for (int j = 0; j < 4; ++j)
        acc[i][j] = __builtin_amdgcn_mfma_f32_16x16x32_bf16(a[i], b[j], acc[i][j], 0, 0, 0);
  }
}

// ---- 128-row variant: wave covers rows wm*64..+63 (4 i-subtiles), same swizzle. ----
__device__ __forceinline__ void gemm_core128s(const unsigned short* As, const unsigned short* Bs,
                                              floatx4 acc[4][4], int wm, int wn, int lane) {
  const int rb = lane & 15;
  const int kg = (lane >> 4) * 8;
  const int xv = (rb & 7) * 8;
#pragma unroll
  for (int kk = 0; kk < 64; kk += 32) {
    const int co = (kk + kg) ^ xv;
    short8 a[4], b[4];
#pragma unroll
    for (int i = 0; i < 4; ++i)
      a[i] = *(const short8*)&As[(wm * 64 + i * 16 + rb) * 64 + co];
#pragma unroll
    for (int j = 0; j < 4; ++j)
      b[j] = *(const short8*)&Bs[(wn * 64 + j * 16 + rb) * 64 + co];
#pragma unroll
    for (int i = 0; i < 4; ++i)
#pragma unroll
      for (int j = 0; j < 4; ++j)
        acc[i][j] = __builtin_amdgcn_mfma_f32_16x16x32_bf16(a[i], b[j], acc[i][j], 0, 0, 0);
  }
}

__device__ __forceinline__ void stageA_emb(unsigned short* As, const float* table,
                                           const int* labels, int m0, int k0, int tid) {
  int r = tid >> 3, kc = (tid & 7) * 8;
#pragma unroll
  for (int p = 0; p < 2; ++p) {
    int row = r + p * 32;
    const float* s = table + (size_t)labels[m0 + row] * ED + k0 + kc;
    *(uint4*)&As[row * LDA + kc] = cvt8hi(s);
  }
}

__device__ __forceinline__ void stageB(unsigned short* Bs, const unsigned short* src, int ldB, int tid) {
  int r = tid >> 3, kc = (tid & 7) * 8;
#pragma unroll
  for (int p = 0; p < 4; ++p)
    *(uint4*)&Bs[(r + p * 32) * LDA + kc] = *(const uint4*)(src + (size_t)(r + p * 32) * ldB + kc);
}

// ---- LAUNCH 1 (fused): blocks 0..1023 cvtw; 1024 beta_1 copy; 1025..1152 trW. ----
__global__ __launch_bounds__(256) void k_phase1(const float* __restrict__ Win,
                                                const float* __restrict__ Wsani,
                                                const float* __restrict__ Wout,
                                                unsigned short* __restrict__ dWin,
                                                unsigned short* __restrict__ dBcat1,
                                                unsigned short* __restrict__ dWsLo,
                                                unsigned short* __restrict__ dWout,
                                                const float* __restrict__ bsani,
                                                float* __restrict__ beta,
                                                unsigned short* __restrict__ Phi,
                                                unsigned short* __restrict__ Plo) {
  __shared__ float t[64][65];
  if (blockIdx.x >= 1025) {
    int bidt = blockIdx.x - 1025;
    int mat = bidt >> 6, tile = bidt & 63;
    int a0 = (tile >> 3) * 64, b0 = (tile & 7) * 64;
    int coloff = (mat == 0) ? 512 : 0;   // P_{1,0}=W2^T, P_{1,1}=W1^T
    for (int pp = 0; pp < 16; ++pp) {
      int idx = pp * 256 + threadIdx.x, rr = idx >> 6, cc = idx & 63;
      t[rr][cc] = Wsani[(size_t)(b0 + rr) * 1024 + coloff + a0 + cc];
    }
    __syncthreads();
    for (int pp = 0; pp < 16; ++pp) {
      int idx = pp * 256 + threadIdx.x, rr = idx >> 6, cc = idx & 63;
      float f = t[cc][rr];
      unsigned short hi = f2b(f);
      size_t o = (size_t)mat * 262144 + (size_t)(a0 + rr) * 512 + b0 + cc;
      Phi[o] = hi;
      Plo[o] = f2b(f - b2f(hi));
    }
    return;
  }
  if (blockIdx.x == 1024) {
    int tt = threadIdx.x;
    beta[tt] = bsani[tt];
    beta[tt + 256] = bsani[tt + 256];
    return;
  }
  int i = blockIdx.x * 256 + threadIdx.x;  // float4 index, total 262144
  if (i < 65536 || i >= 196608) {
    const float* src = (i < 65536) ? Win : Wout;
    unsigned short* dst = (i < 65536) ? dWin : dWout;
    int off = (i < 65536) ? i : i - 196608;
    floatx4 v = *(const floatx4*)(src + (size_t)off * 4);
    uint2 u;
    u.x = (unsigned)f2b(v.x) | ((unsigned)f2b(v.y) << 16);
    u.y = (unsigned)f2b(v.z) | ((unsigned)f2b(v.w) << 16);
    *(uint2*)(dst + (size_t)off * 4) = u;
  } else {
    int off = i - 65536;
    floatx4 v = *(const floatx4*)(Wsani + (size_t)off * 4);
    float f[4] = {v.x, v.y, v.z, v.w};
    unsigned short hb[4], lb[4];
#pragma unroll
    for (int k = 0; k < 4; ++k) {
      hb[k] = f2b(f[k]);
      lb[k] = f2b(f[k] - b2f(hb[k]));
    }
    uint2 h, l;
    h.x = hb[0] | ((unsigned)hb[1] << 16); h.y = hb[2] | ((unsigned)hb[3] << 16);
    l.x = lb[0] | ((unsigned)lb[1] << 16); l.y = lb[2] | ((unsigned)lb[3] << 16);
    *(uint2*)(dBcat1 + (size_t)off * 4) = h;
    *(uint2*)(dWsLo + (size_t)off * 4) = l;
  }
}

// ---- coefficient chain (FUSED): see round 15/16 (unchanged, bit-identical). ----
__global__ __launch_bounds__(256) void k_coef(const unsigned short* __restrict__ Phi,
                                              const unsigned short* __restrict__ Plo,
                                              unsigned short* __restrict__ PhiOut,
                                              unsigned short* __restrict__ PloOut,
                                              const unsigned short* __restrict__ WsHi,
                                              const unsigned short* __restrict__ WsLo,
                                              int m,
                                              unsigned short* __restrict__ BcatOut,
                                              const float* __restrict__ WsF,
                                              const float* __restrict__ bF,
                                              const float* __restrict__ bprev,
                                              float* __restrict__ bout,
                                              int nemb,
                                              const float* __restrict__ table,
                                              const int* __restrict__ labels,
                                              const unsigned short* __restrict__ Win_b,
                                              const float* __restrict__ b_in,
                                              unsigned short* __restrict__ xt,
                                              unsigned short* __restrict__ outs0) {
  __shared__ unsigned short lds[24576];   // 48 KB, shared by all branches
  const int ngemm = (m + 2) * 32;
  const int tid = threadIdx.x;

  if ((int)blockIdx.x >= ngemm + 128) {
    // ---- emb branch: x_t = bf16(emb @ W_in^T + b_in); outs[0] = x_t[0] ----
    const int ebid = blockIdx.x - (ngemm + 128);   // 0..nemb-1
    unsigned short* As = lds;                       // 64 x LDA (4608 shorts)
    unsigned short* Bs = lds + 4608;                // 128 x LDA (9216 shorts)
    int mtile = ebid >> 2, ntile = ebid & 3;
    int m0 = mtile * 64, n0 = ntile * 128;
    int lane = tid & 63, wave = tid >> 6, wm = wave >> 1, wn = wave & 1;
    floatx4 acc[2][4] = {};
    for (int k0 = 0; k0 < 512; k0 += 64) {
      stageA_emb(As, table, labels, m0, k0, tid);
      stageB(Bs, Win_b + (size_t)n0 * 512 + k0, 512, tid);
      __syncthreads();
      gemm_core24(As, Bs, acc, wm, wn, lane);
      __syncthreads();
    }
    int rb = lane & 15, rg = (lane >> 4) * 4;
#pragma unroll
    for (int i = 0; i < 2; ++i)
#pragma unroll
      for (int j = 0; j < 4; ++j) {
        int col = n0 + wn * 64 + j * 16 + rb;
        float bv = b_in[col];
#pragma unroll
        for (int reg = 0; reg < 4; ++reg) {
          int mm = m0 + wm * 32 + i * 16 + rg + reg;
          int n = mm >> 6, l = mm & 63;
          unsigned short v = f2b(acc[i][j][reg] + bv);
          xt[((size_t)l * NB + n) * HD + col] = v;
          if (l == 0) outs0[(size_t)n * HD + col] = v;
        }
      }
    return;
  }

  if ((int)blockIdx.x >= ngemm) {
    const int bb = blockIdx.x - ngemm;
    const int w = tid >> 6, lane2 = tid & 63;
    const int i = bb * 4 + w;
    float p = 0.f;
    for (int k = lane2; k < 512; k += 64)
      p += (WsF[(size_t)i * 1024 + k] + WsF[(size_t)i * 1024 + 512 + k]) * bprev[k];
#pragma unroll
    for (int off = 32; off > 0; off >>= 1) p += __shfl_down(p, off, 64);
    if (lane2 == 0) bout[i] = p + bF[i];
    return;
  }

  // ---- coef GEMM branch ----
  unsigned short* const A0 = lds;
  unsigned short* const A1 = lds + 4096;
  unsigned short* const B0 = lds + 8192;
  unsigned short* const B1 = lds + 16384;
  const int j = blockIdx.x >> 5, tile = blockIdx.x & 31;
  const int k0r = (tile >> 2) * 64, n0 = (tile & 3) * 128;
  const int lane = tid & 63, wave = tid >> 6, wm = wave >> 1, wn = wave & 1;
  const int rr_ = tid >> 3;
  const int kcs = (((tid & 7) ^ ((tid >> 3) & 7))) * 8;  // swizzled source column
  const int t_first = (j <= m) ? 0 : 1;
  const int nterms = ((j <= m) ? 1 : 0) + ((j >= 1) ? 1 : 0);
  const int nsteps = nterms * 24;         // 3 hi/lo passes x 8 t0-steps per term

  floatx4 acc[2][4] = {};

#define STAGE_C(Ab, Bb, u)                                                           \
  { int term_ = t_first + (((u) >= 24) ? 1 : 0);                                     \
    int v_ = ((u) >> 3) % 3;                                                         \
    int t0_ = ((u) & 7) * 64;                                                        \
    const unsigned short* As_ = ((v_ == 2) ? Plo : Phi)                              \
        + (size_t)(term_ ? (j - 1) : j) * 262144 + (size_t)k0r * 512 + t0_;          \
    const unsigned short* Bs_ = ((v_ == 1) ? WsLo : WsHi)                            \
        + (size_t)n0 * 1024 + (term_ ? 0 : 512) + t0_;                               \
    unsigned short* lA = (Ab) + (tid >> 6) * 512;                                    \
    unsigned short* lB = (Bb) + (tid >> 6) * 512;                                    \
    gl_lds16(As_ + (size_t)rr_ * 512 + kcs, lA);                                     \
    gl_lds16(As_ + (size_t)(rr_ + 32) * 512 + kcs, lA + 2048);                       \
    gl_lds16(Bs_ + (size_t)rr_ * 1024 + kcs, lB);                                    \
    gl_lds16(Bs_ + (size_t)(rr_ + 32) * 1024 + kcs, lB + 2048);                      \
    gl_lds16(Bs_ + (size_t)(rr_ + 64) * 1024 + kcs, lB + 4096);                      \
    gl_lds16(Bs_ + (size_t)(rr_ + 96) * 1024 + kcs, lB + 6144); }

  STAGE_C(A0, B0, 0)
  __syncthreads();
  for (int u = 0; u < nsteps; u += 2) {
    if (u + 1 < nsteps) STAGE_C(A1, B1, u + 1)
    gemm_core64s(A0, B0, acc, wm, wn, lane);
    __syncthreads();
    if (u + 2 < nsteps) STAGE_C(A0, B0, u + 2)
    gemm_core64s(A1, B1, acc, wm, wn, lane);
    __syncthreads();
  }
#undef STAGE_C

  unsigned short* CtT = lds;             // [128][72] (9216 shorts <= 24576)
  const int rb = lane & 15, rg = (lane >> 4) * 4;
#pragma unroll
  for (int i = 0; i < 2; ++i)
#pragma unroll
    for (int jj = 0; jj < 4; ++jj) {
      int colL = wn * 64 + jj * 16 + rb;     // 0..127 local (= Bcat row)
      int col = n0 + colL;
#pragma unroll
      for (int reg = 0; reg < 4; ++reg) {
        int row = wm * 32 + i * 16 + rg + reg;
        float f = acc[i][jj][reg];
        unsigned short hi = f2b(f);
        size_t o = (size_t)j * 262144 + (size_t)(k0r + row) * 512 + col;
        PhiOut[o] = hi;
        PloOut[o] = f2b(f - b2f(hi));
        CtT[colL * 72 + row] = hi;
      }
    }
  __syncthreads();
  const int rr2 = m + 1;
  const int ldB2 = (rr2 + 1) * 512;
  const int q = rr2 - j;
  const int rowi = tid >> 1, half = tid & 1;   // 256 thr = 128 rows x 2 halves
  unsigned short* dB = BcatOut + (size_t)(n0 + rowi) * ldB2 + q * 512 + k0r + half * 32;
  const unsigned short* sB = &CtT[rowi * 72 + half * 32];
#pragma unroll
  for (int c = 0; c < 4; ++c)
    *(uint4*)(dB + c * 8) = *(const uint4*)(sB + c * 8);
}

// ---- phase 2a (j<=8): PAIRED step -- one block = full 128-row slab x 128 cols.
//      B panel staged ONCE per K-step for both row-halves (1.5x traffic cut,
//      2x MFMA per barrier). Same K-order per element -> bit-identical. ----
__global__ __launch_bounds__(256) void k_step2(const unsigned short* __restrict__ src,
                                               unsigned short* __restrict__ dst,
                                               unsigned short* __restrict__ outs,
                                               const unsigned short* __restrict__ Bcat,
                                               const float* __restrict__ beta,
                                               int L_prev, int m, int nmain, int g) {
  __shared__ unsigned short lds[32768];   // A0[8192] B0[8192] A1[8192] B1[8192] = 64 KB
  unsigned short* const A0 = lds;
  unsigned short* const B0 = lds + 8192;
  unsigned short* const A1 = lds + 16384;
  unsigned short* const B1 = lds + 24576;
  const int tid = threadIdx.x, bid = blockIdx.x;
  const int mainWG = 16 * g;   // 8 XCDs x g slabs x 2 n-panels
  int r, s, n0;
  if (bid < mainWG) {
    const int xcd = bid & 7, w = bid >> 3;
    const int sgrp = xcd >> 1, ngrp = xcd & 1;
    const int s_rel = sgrp * g + (w >> 1);
    if (s_rel >= nmain) return;                    // uniform exit (pre-barrier)
    n0 = (ngrp * 2 + (w & 1)) * 128;
    r = m; s = L_prev + m + s_rel;
  } else {
    const int db = bid - mainWG;
    r = 1 + (db >> 2);
    n0 = (db & 3) * 128;
    s = L_prev + r;
  }
  const int ldB = (r + 1) * 512;
  const unsigned short* Bp = Bcat + (size_t)262144 * (((r - 1) * (r + 2)) >> 1);
  const unsigned short* abase = src + (size_t)(s - r) * NH;     // full slab
  const float* bet = beta + (size_t)(r - 1) * 512;
  const int nk = (r + 1) * 8;
  const int lane = tid & 63, wave = tid >> 6, wm = wave >> 1, wn = wave & 1;
  const int rr_ = tid >> 3;
  const int kcs = (((tid & 7) ^ ((tid >> 3) & 7))) * 8;

  floatx4 acc[4][4] = {};

#define STAGE2(Ab, Bb, kcol)                                                         \
  { int q_ = (kcol) >> 9, ac_ = (kcol) & 511;                                        \
    const unsigned short* a0_ = abase + (size_t)q_ * NH + ac_;                       \
    unsigned short* lA = (Ab) + (tid >> 6) * 512;                                    \
    unsigned short* lB = (Bb) + (tid >> 6) * 512;                                    \
    gl_lds16(a0_ + (size_t)rr_ * HD + kcs, lA);                                      \
    gl_lds16(a0_ + (size_t)(rr_ + 32) * HD + kcs, lA + 2048);                        \
    gl_lds16(a0_ + (size_t)(rr_ + 64) * HD + kcs, lA + 4096);                        \
    gl_lds16(a0_ + (size_t)(rr_ + 96) * HD + kcs, lA + 6144);                        \
    gl_lds16(Bp + (size_t)(n0 + rr_) * ldB + (kcol) + kcs, lB);                      \
    gl_lds16(Bp + (size_t)(n0 + rr_ + 32) * ldB + (kcol) + kcs, lB + 2048);          \
    gl_lds16(Bp + (size_t)(n0 + rr_ + 64) * ldB + (kcol) + kcs, lB + 4096);          \
    gl_lds16(Bp + (size_t)(n0 + rr_ + 96) * ldB + (kcol) + kcs, lB + 6144); }

  STAGE2(A0, B0, 0)
  __syncthreads();
  for (int k = 0; k < nk; k += 2) {
    if (k + 1 < nk) STAGE2(A1, B1, (k + 1) * 64)
    gemm_core128s(A0, B0, acc, wm, wn, lane);
    __syncthreads();
    if (k + 2 < nk) STAGE2(A0, B0, (k + 2) * 64)
    gemm_core128s(A1, B1, acc, wm, wn, lane);
    __syncthreads();
  }
#undef STAGE2

  // ---- epilogue: stage C (128x128 bf16) in LDS, then full-line stores ----
  unsigned short* Ct = lds;            // 128 x LDC = 17408 shorts <= 32768
  const int rbc = lane & 15, rg = (lane >> 4) * 4;
#pragma unroll
  for (int i = 0; i < 4; ++i)
#pragma unroll
    for (int j = 0; j < 4; ++j) {
      int col = wn * 64 + j * 16 + rbc;            // 0..127 local
      float bv = bet[n0 + col];
#pragma unroll
      for (int reg = 0; reg < 4; ++reg) {
        int row = wm * 64 + i * 16 + rg + reg;     // 0..127 local
        Ct[row * LDC + col] = f2b(acc[i][j][reg] + bv);
      }
    }
  __syncthreads();
  const bool wdst = (r == m);
  const bool wout = (r < m) || (s == L_prev + m);  // outs[li] = h(li,li)
  unsigned short* d1 = dst  + (size_t)s * NH + n0;
  unsigned short* d2 = outs + (size_t)s * NH + n0;
  const int lrow = tid >> 4, lcol = (tid & 15) * 8;  // 16 thr x 16B = 256B/row
#pragma unroll
  for (int sweep = 0; sweep < 8; ++sweep) {
    int row = sweep * 16 + lrow;
    uint4 v = *(const uint4*)&Ct[row * LDC + lcol];
    if (wdst) *(uint4*)(d1 + (size_t)row * HD + lcol) = v;
    if (wout) *(uint4*)(d2 + (size_t)row * HD + lcol) = v;
  }
}

// ---- phase 2b (j>=9): proven round-16 step kernel, unchanged. ----
__global__ __launch_bounds__(256) void k_step(const unsigned short* __restrict__ src,
                                              unsigned short* __restrict__ dst,
                                              unsigned short* __restrict__ outs,
                                              const unsigned short* __restrict__ Bcat,
                                              const float* __restrict__ beta,
                                              int L_prev, int m, int nmain, int g) {
  __shared__ unsigned short lds[24576];   // A0[4096] A1[4096] B0[8192] B1[8192] = 48 KB
  unsigned short* const A0 = lds;
  unsigned short* const A1 = lds + 4096;
  unsigned short* const B0 = lds + 8192;
  unsigned short* const B1 = lds + 16384;
  const int tid = threadIdx.x, bid = blockIdx.x;
  const int mainWG = 32 * g;   // 8 XCDs x g slabs x 4 (2 nb0 x 2 n-panels)
  int r, s, nb0, n0;
  if (bid < mainWG) {
    const int xcd = bid & 7, w = bid >> 3;        // dispatch round-robin -> XCD
    const int sgrp = xcd >> 1, ngrp = xcd & 1;
    const int s_rel = sgrp * g + (w >> 2);
    if (s_rel >= nmain) return;                    // uniform block exit (pre-barrier)
    const int sub2 = w & 3;
    nb0 = (sub2 >> 1) * 64;
    n0 = (ngrp * 2 + (sub2 & 1)) * 128;
    r = m; s = L_prev + m + s_rel;
  } else {
    const int db = bid - mainWG;
    r = 1 + (db >> 3);
    const int sub = db & 7;
    nb0 = (sub >> 2) * 64; n0 = (sub & 3) * 128;
    s = L_prev + r;
  }
  const int ldB = (r + 1) * 512;
  const unsigned short* Bp = Bcat + (size_t)262144 * (((r - 1) * (r + 2)) >> 1);
  const unsigned short* abase = src + (size_t)(s - r) * NH + (size_t)nb0 * HD;
  const float* bet = beta + (size_t)(r - 1) * 512;
  const int nk = (r + 1) * 8;        // always even (16,24,32,40)
  const int lane = tid & 63, wave = tid >> 6, wm = wave >> 1, wn = wave & 1;
  const int rr_ = tid >> 3;
  const int kcs = (((tid & 7) ^ ((tid >> 3) & 7))) * 8;  // swizzled source column

  floatx4 acc[2][4] = {};

#define STAGE(Ab, Bb, kcol)                                                          \
  { int q_ = (kcol) >> 9, ac_ = (kcol) & 511;                                        \
    const unsigned short* a0_ = abase + (size_t)q_ * NH + ac_;                       \
    unsigned short* lA = (Ab) + (tid >> 6) * 512;                                    \
    unsigned short* lB = (Bb) + (tid >> 6) * 512;                                    \
    gl_lds16(a0_ + (size_t)rr_ * HD + kcs, lA);                                      \
    gl_lds16(a0_ + (size_t)(rr_ + 32) * HD + kcs, lA + 2048);                        \
    gl_lds16(Bp + (size_t)(n0 + rr_) * ldB + (kcol) + kcs, lB);                      \
    gl_lds16(Bp + (size_t)(n0 + rr_ + 32) * ldB + (kcol) + kcs, lB + 2048);          \
    gl_lds16(Bp + (size_t)(n0 + rr_ + 64) * ldB + (kcol) + kcs, lB + 4096);          \
    gl_lds16(Bp + (size_t)(n0 + rr_ + 96) * ldB + (kcol) + kcs, lB + 6144); }

  STAGE(A0, B0, 0)
  __syncthreads();                     // drain prologue loads
  for (int k = 0; k < nk; k += 2) {
    if (k + 1 < nk) STAGE(A1, B1, (k + 1) * 64)   // prefetch hides under MFMA
    gemm_core64s(A0, B0, acc, wm, wn, lane);
    __syncthreads();                               // drain prefetch + WAR-protect A0/B0
    if (k + 2 < nk) STAGE(A0, B0, (k + 2) * 64)
    gemm_core64s(A1, B1, acc, wm, wn, lane);
    __syncthreads();
  }
#undef STAGE

  unsigned short* Ct = lds;            // 64 x LDC = 8704 shorts <= 24576
  const int rbc = lane & 15, rg = (lane >> 4) * 4;
#pragma unroll
  for (int i = 0; i < 2; ++i)
#pragma unroll
    for (int j = 0; j < 4; ++j) {
      int col = wn * 64 + j * 16 + rbc;            // 0..127 local
      float bv = bet[n0 + col];
#pragma unroll
      for (int reg = 0; reg < 4; ++reg) {
        int row = wm * 32 + i * 16 + rg + reg;     // 0..63 local
        Ct[row * LDC + col] = f2b(acc[i][j][reg] + bv);
      }
    }
  __syncthreads();
  const bool wdst = (r == m);
  const bool wout = (r < m) || (s == L_prev + m);  // outs[li] = h(li,li)
  unsigned short* d1 = dst  + (size_t)s * NH + (size_t)nb0 * HD + n0;
  unsigned short* d2 = outs + (size_t)s * NH + (size_t)nb0 * HD + n0;
  const int lrow = tid >> 4, lcol = (tid & 15) * 8;  // 16 thr x 16B = 256B/row
#pragma unroll
  for (int sweep = 0; sweep < 4; ++sweep) {
    int row = sweep * 16 + lrow;
    uint4 v = *(const uint4*)&Ct[row * LDC + lcol];
    if (wdst) *(uint4*)(d1 + (size_t)row * HD + lcol) = v;
    if (wout) *(uint4*)(d2 + (size_t)row * HD + lcol) = v;
  }
}

// ---- phase 3 (TEMPLATE): Y = outs_flat @ W_out^T + b_out (fp32 out). ----
__global__ __launch_bounds__(256) void k_gemm_out(const unsigned short* __restrict__ outs,
                                                  const unsigned short* __restrict__ Wb,
                                                  const float* __restrict__ bias,
                                                  float* __restrict__ Y) {
  __shared__ unsigned short lds[24576];
  unsigned short* const A0 = lds;
  unsigned short* const A1 = lds + 4096;
  unsigned short* const B0 = lds + 8192;
  unsigned short* const B1 = lds + 16384;
  const int tid = threadIdx.x;
  const int mtile = blockIdx.x >> 2, ntile = blockIdx.x & 3;
  const int m0 = mtile * 64, n0 = ntile * 128;
  const int lane = tid & 63, wave = tid >> 6, wm = wave >> 1, wn = wave & 1;
  const int rr_ = tid >> 3;
  const int kcs = (((tid & 7) ^ ((tid >> 3) & 7))) * 8;
  const unsigned short* abase = outs + (size_t)m0 * 512;
  const unsigned short* Bp = Wb + (size_t)n0 * 512;

  floatx4 acc[2][4] = {};

#define STAGE_O(Ab, Bb, kcol)                                                        \
  { unsigned short* lA = (Ab) + (tid >> 6) * 512;                                    \
    unsigned short* lB = (Bb) + (tid >> 6) * 512;                                    \
    gl_lds16(abase + (size_t)rr_ * 512 + (kcol) + kcs, lA);                          \
    gl_lds16(abase + (size_t)(rr_ + 32) * 512 + (kcol) + kcs, lA + 2048);            \
    gl_lds16(Bp + (size_t)rr_ * 512 + (kcol) + kcs, lB);                             \
    gl_lds16(Bp + (size_t)(rr_ + 32) * 512 + (kcol) + kcs, lB + 2048);               \
    gl_lds16(Bp + (size_t)(rr_ + 64) * 512 + (kcol) + kcs, lB + 4096);               \
    gl_lds16(Bp + (size_t)(rr_ + 96) * 512 + (kcol) + kcs, lB + 6144); }

  STAGE_O(A0, B0, 0)
  __syncthreads();
  for (int k = 0; k < 8; k += 2) {
    if (k + 1 < 8) STAGE_O(A1, B1, (k + 1) * 64)
    gemm_core64s(A0, B0, acc, wm, wn, lane);
    __syncthreads();
    if (k + 2 < 8) STAGE_O(A0, B0, (k + 2) * 64)
    gemm_core64s(A1, B1, acc, wm, wn, lane);
    __syncthreads();
  }
#undef STAGE_O

  float* Ctf = (float*)lds;            // 64 x LDCF x 4B = 33792 B <= 49152
  const int rbc = lane & 15, rg = (lane >> 4) * 4;
#pragma unroll
  for (int i = 0; i < 2; ++i)
#pragma unroll
    for (int j = 0; j < 4; ++j) {
      int col = wn * 64 + j * 16 + rbc;
      float bv = bias[n0 + col];
#pragma unroll
      for (int reg = 0; reg < 4; ++reg) {
        int row = wm * 32 + i * 16 + rg + reg;
        Ctf[row * LDCF + col] = acc[i][j][reg] + bv;
      }
    }
  __syncthreads();
  const int lrow = tid >> 5, lc = (tid & 31) * 4;   // 32 thr x 16B = 512B/row
#pragma unroll
  for (int sweep = 0; sweep < 8; ++sweep) {
    int row = sweep * 8 + lrow;
    uint4 v = *(const uint4*)&Ctf[row * LDCF + lc];
    *(uint4*)&Y[(size_t)(m0 + row) * 512 + n0 + lc] = v;
  }
}

// ---- loss: per n, column-softmax over 64 consecutive Y rows, dot with emb ----
__global__ __launch_bounds__(256) void k_loss(const float* __restrict__ Y,
                                              const float* __restrict__ table,
                                              const int* __restrict__ labels,
                                              float* __restrict__ partials) {
  int n = blockIdx.x, tid = threadIdx.x;
  float total = 0.f;
#pragma unroll
  for (int e2 = 0; e2 < 2; ++e2) {
    int e = e2 * 256 + tid;
    float mx = -1e30f;
    for (int l = 0; l < 64; ++l)
      mx = fmaxf(mx, Y[(size_t)(n * 64 + l) * 512 + e]);
    float se = 0.f;
    for (int l = 0; l < 64; ++l)
      se += expf(Y[(size_t)(n * 64 + l) * 512 + e] - mx);
    float lse = mx + logf(se);
    for (int l = 0; l < 64; ++l) {
      float embv = table[(size_t)labels[n * 64 + l] * ED + e];
      total += embv * (Y[(size_t)(n * 64 + l) * 512 + e] - lse);
    }
  }
  __shared__ float red[256];
  red[tid] = total;
  __syncthreads();
  for (int s2 = 128; s2 > 0; s2 >>= 1) {
    if (tid < s2) red[tid] += red[tid + s2];
    __syncthreads();
  }
  if (tid == 0) partials[n] = red[0];
}

__global__ void k_final(const float* __restrict__ partials, float* __restrict__ out) {
  if (threadIdx.x == 0) {
    double s = 0.0;
    for (int i = 0; i < 128; ++i) s += (double)partials[i];
    out[0] = (float)(-s / 65536.0);
  }
}

extern "C" void kernel_launch(void* const* d_in, const int* in_sizes, int n_in,
                              void* d_out, int out_size, void* d_ws, size_t ws_size,
                              hipStream_t stream) {
  const int*   labels = (const int*)d_in[0];
  const float* table  = (const float*)d_in[1];
  const float* W_in   = (const float*)d_in[2];
  const float* b_in   = (const float*)d_in[3];
  const float* W_sani = (const float*)d_in[4];
  const float* b_sani = (const float*)d_in[5];
  const float* W_out  = (const float*)d_in[6];
  const float* b_out  = (const float*)d_in[7];

  char* ws = (char*)d_ws;
  unsigned short* Win_b  = (unsigned short*)(ws + OFF_WIN);
  unsigned short* Wout_b = (unsigned short*)(ws + OFF_WOUT);
  unsigned short* xt     = (unsigned short*)(ws + OFF_XT);
  unsigned short* lvl0   = (unsigned short*)(ws + OFF_LVL0);
  unsigned short* lvl1   = (unsigned short*)(ws + OFF_LVL1);
  unsigned short* outs   = (unsigned short*)(ws + OFF_OUTS);
  unsigned short* PhiA   = (unsigned short*)(ws + OFF_PHA);
  unsigned short* PloA   = (unsigned short*)(ws + OFF_PLA);
  unsigned short* PhiB   = (unsigned short*)(ws + OFF_PHB);
  unsigned short* PloB   = (unsigned short*)(ws + OFF_PLB);
  unsigned short* Bcat   = (unsigned short*)(ws + OFF_BCAT);
  float*          beta   = (float*)(ws + OFF_BETA);
  float*          parts  = (float*)(ws + OFF_PART);
  unsigned short* WsLo   = (unsigned short*)(ws + OFF_WSLO);
  float*          Y      = (float*)(ws + OFF_Y);

  // Launch 1: cvtw (1024) + beta_1 copy (1) + trW (128)
  k_phase1<<<1153, 256, 0, stream>>>(W_in, W_sani, W_out, Win_b, Bcat, WsLo, Wout_b,
                                     b_sani, beta, PhiA, PloA);

  // Launch 2: coef1 (96) + bias beta_2 (128) + emb GEMM (512, independent, overlaps)
  k_coef<<< 96 + 128 + 512, 256, 0, stream>>>(PhiA, PloA, PhiB, PloB, Bcat, WsLo, 1,
                                        Bcat + 524288, W_sani, b_sani,
                                        beta, beta + 512, 512,
                                        table, labels, Win_b, b_in, xt, outs);
  k_coef<<<128 + 128, 256, 0, stream>>>(PhiB, PloB, PhiA, PloA, Bcat, WsLo, 2,
                                        Bcat + 1310720, W_sani, b_sani,
                                        beta + 512, beta + 1024, 0,
                                        table, labels, Win_b, b_in, xt, outs);
  k_coef<<<160 + 128, 256, 0, stream>>>(PhiA, PloA, PhiB, PloB, Bcat, WsLo, 3,
                                        Bcat + 2359296, W_sani, b_sani,
                                        beta + 1024, beta + 1536, 0,
                                        table, labels, Win_b, b_in, xt, outs);

  // 16 multi-level steps (15 x m=4, 1 x m=3); paired kernel for big grids (j<=8)
  const unsigned short* srcp = xt;
  for (int j = 1; j <= 16; ++j) {
    int L_prev = 4 * (j - 1);
    int m = (j == 16) ? 3 : 4;
    int nmain = 64 - (L_prev + m);
    int g = (nmain + 3) >> 2;          // slabs per s-group (4 s-groups)
    unsigned short* dstp = ((j - 1) & 1) ? lvl1 : lvl0;
    if (j <= 8)
      k_step2<<<16 * g + (m - 1) * 4, 256, 0, stream>>>(srcp, dstp, outs, Bcat, beta,
                                                        L_prev, m, nmain, g);
    else
      k_step<<<32 * g + (m - 1) * 8, 256, 0, stream>>>(srcp, dstp, outs, Bcat, beta,
                                                       L_prev, m, nmain, g);
    srcp = dstp;
  }

  k_gemm_out<<<512, 256, 0, stream>>>(outs, Wout_b, b_out, Y);
  k_loss<<<128, 256, 0, stream>>>(Y, table, labels, parts);
  k_final<<<1, 64, 0, stream>>>(parts, (float*)d_out);
}

// Round 18
// 580.252 us; speedup vs baseline: 1.0013x; 1.0013x over previous
//
#include <hip/hip_runtime.h>
#include <hip/hip_bf16.h>

typedef __attribute__((ext_vector_type(8))) short short8;
typedef __attribute__((ext_vector_type(4))) float floatx4;

#define NB 128      // batch N
#define LS 64       // seq L
#define HD 512      // hidden H
#define ED 512      // embed E
#define NH 65536    // NB*HD elements per s-slab
#define LDA 72      // LDS tile stride for reg-staged kernels (64 + 8 pad)
#define LDC 136     // LDS C-tile stride bf16 (128 + 8 pad)
#define LDCF 132    // LDS C-tile stride f32 (128 + 4 pad)

// ws layout (byte offsets)
#define OFF_WIN    0ull          // W_in bf16   [512*512]
#define OFF_WOUT   524288ull     // W_out bf16  [512*512]
#define OFF_XT     1048576ull    // x_t bf16    [64][128][512]  (= level 0)
#define OFF_LVL0   9437184ull    // level ping  bf16 [64][128][512]
#define OFF_LVL1   17825792ull   // level pong  bf16 [64][128][512]
#define OFF_OUTS   26214400ull   // outs bf16   [64][128][512]
#define OFF_PHA    34603008ull   // P hi ping  bf16 (5x 512x512, 2.62 MB)
#define OFF_PLA    37224448ull   // P lo ping
#define OFF_PHB    39845888ull   // P hi pong
#define OFF_PLB    42467328ull   // P lo pong
#define OFF_BCAT   45088768ull   // Bcat_1..4 bf16 concat (7 MB); Bcat_1 == WsHi
#define OFF_BETA   52428800ull   // beta_1..4 f32 [4][512]
#define OFF_PART   52436992ull   // partials f32 [128]
#define OFF_WSLO   52437504ull   // W_sani lo bf16 [512*1024] (1 MB)
#define OFF_Y      OFF_LVL0      // Y f32 [8192][512] aliases lvl bufs after recurrence

static __device__ __forceinline__ unsigned short f2b(float f) {
  unsigned u = __float_as_uint(f);
  u += 0x7fffu + ((u >> 16) & 1u);   // round-to-nearest-even
  return (unsigned short)(u >> 16);
}
static __device__ __forceinline__ float b2f(unsigned short h) {
  return __uint_as_float(((unsigned)h) << 16);
}

// async global -> LDS, 16B per lane; LDS dest = wave-uniform base + lane*16
static __device__ __forceinline__ void gl_lds16(const unsigned short* g, unsigned short* l) {
  __builtin_amdgcn_global_load_lds(
      (const __attribute__((address_space(1))) void*)g,
      (__attribute__((address_space(3))) void*)l, 16, 0, 0);
}

// load 8 consecutive f32, produce bf16x8 packed (hi only; used for emb gather)
static __device__ __forceinline__ uint4 cvt8hi(const float* s) {
  floatx4 f0 = *(const floatx4*)s;
  floatx4 f1 = *(const floatx4*)(s + 4);
  float f[8] = {f0.x, f0.y, f0.z, f0.w, f1.x, f1.y, f1.z, f1.w};
  unsigned short b[8];
#pragma unroll
  for (int k = 0; k < 8; ++k) b[k] = f2b(f[k]);
  uint4 u;
  u.x = b[0] | ((unsigned)b[1] << 16); u.y = b[2] | ((unsigned)b[3] << 16);
  u.z = b[4] | ((unsigned)b[5] << 16); u.w = b[6] | ((unsigned)b[7] << 16);
  return u;
}

// ---- padded-LDS GEMM core (emb branch): BM=64, BN=128, 4 waves 2x2 ----
__device__ __forceinline__ void gemm_core24(const unsigned short* As, const unsigned short* Bs,
                                            floatx4 acc[2][4], int wm, int wn, int lane) {
  const int rb = lane & 15;
  const int kg = (lane >> 4) * 8;
#pragma unroll
  for (int kk = 0; kk < 64; kk += 32) {
    short8 a[2], b[4];
#pragma unroll
    for (int i = 0; i < 2; ++i)
      a[i] = *(const short8*)&As[(wm * 32 + i * 16 + rb) * LDA + kk + kg];
#pragma unroll
    for (int j = 0; j < 4; ++j)
      b[j] = *(const short8*)&Bs[(wn * 64 + j * 16 + rb) * LDA + kk + kg];
#pragma unroll
    for (int i = 0; i < 2; ++i)
#pragma unroll
      for (int j = 0; j < 4; ++j)
        acc[i][j] = __builtin_amdgcn_mfma_f32_16x16x32_bf16(a[i], b[j], acc[i][j], 0, 0, 0);
  }
}

// ---- UNPADDED stride-64 core with XOR bank swizzle (64-row tiles). ----
__device__ __forceinline__ void gemm_core64s(const unsigned short* As, const unsigned short* Bs,
                                             floatx4 acc[2][4], int wm, int wn, int lane) {
  const int rb = lane & 15;
  const int kg = (lane >> 4) * 8;
  const int xv = (rb & 7) * 8;       // XOR swizzle, units of 8 shorts (16B)
#pragma unroll
  for (int kk = 0; kk < 64; kk += 32) {
    const int co = (kk + kg) ^ xv;   // kk+kg is a multiple of 8 -> pure slot XOR
    short8 a[2], b[4];
#pragma unroll
    for (int i = 0; i < 2; ++i)
      a[i] = *(const short8*)&As[(wm * 32 + i * 16 + rb) * 64 + co];
#pragma unroll
    for (int j = 0; j < 4; ++j)
      b[j] = *(const short8*)&Bs[(wn * 64 + j * 16 + rb) * 64 + co];
#pragma unroll
    for (int i = 0; i < 2; ++i)
#pragma unroll
      for (int j = 0; j < 4; ++j)
        acc[i][j] = __builtin_amdgcn_mfma_f32_16x16x32_bf16(a[i], b[j], acc[i][j], 0, 0, 0);
  }
}

// ---- 128-row variant: wave covers rows wm*64..+63 (4 i-subtiles), same swizzle. ----
__device__ __forceinline__ void gemm_core128s(const unsigned short* As, const unsigned short* Bs,
                                              floatx4 acc[4][4], int wm, int wn, int lane) {
  const int rb = lane & 15;
  const int kg = (lane >> 4) * 8;
  const int xv = (rb & 7) * 8;
#pragma unroll
  for (int kk = 0; kk < 64; kk += 32) {
    const int co = (kk + kg) ^ xv;
    short8 a[4], b[4];
#pragma unroll
    for (int i = 0; i < 4; ++i)
      a[i] = *(const short8*)&As[(wm * 64 + i * 16 + rb) * 64 + co];
#pragma unroll
    for (int j = 0; j < 4; ++j)
      b[j] = *(const short8*)&Bs[(wn * 64 + j * 16 + rb) * 64 + co];
#pragma unroll
    for (int i = 0; i < 4; ++i)
#pragma unroll
      for (int j = 0; j < 4; ++j)
        acc[i][j] = __builtin_amdgcn_mfma_f32_16x16x32_bf16(a[i], b[j], acc[i][j], 0, 0, 0);
  }
}

__device__ __forceinline__ void stageA_emb(unsigned short* As, const float* table,
                                           const int* labels, int m0, int k0, int tid) {
  int r = tid >> 3, kc = (tid & 7) * 8;
#pragma unroll
  for (int p = 0; p < 2; ++p) {
    int row = r + p * 32;
    const float* s = table + (size_t)labels[m0 + row] * ED + k0 + kc;
    *(uint4*)&As[row * LDA + kc] = cvt8hi(s);
  }
}

__device__ __forceinline__ void stageB(unsigned short* Bs, const unsigned short* src, int ldB, int tid) {
  int r = tid >> 3, kc = (tid & 7) * 8;
#pragma unroll
  for (int p = 0; p < 4; ++p)
    *(uint4*)&Bs[(r + p * 32) * LDA + kc] = *(const uint4*)(src + (size_t)(r + p * 32) * ldB + kc);
}

// ---- LAUNCH 1 (fused): blocks 0..1023 cvtw; 1024 beta_1 copy; 1025..1152 trW. ----
__global__ __launch_bounds__(256) void k_phase1(const float* __restrict__ Win,
                                                const float* __restrict__ Wsani,
                                                const float* __restrict__ Wout,
                                                unsigned short* __restrict__ dWin,
                                                unsigned short* __restrict__ dBcat1,
                                                unsigned short* __restrict__ dWsLo,
                                                unsigned short* __restrict__ dWout,
                                                const float* __restrict__ bsani,
                                                float* __restrict__ beta,
                                                unsigned short* __restrict__ Phi,
                                                unsigned short* __restrict__ Plo) {
  __shared__ float t[64][65];
  if (blockIdx.x >= 1025) {
    int bidt = blockIdx.x - 1025;
    int mat = bidt >> 6, tile = bidt & 63;
    int a0 = (tile >> 3) * 64, b0 = (tile & 7) * 64;
    int coloff = (mat == 0) ? 512 : 0;   // P_{1,0}=W2^T, P_{1,1}=W1^T
    for (int pp = 0; pp < 16; ++pp) {
      int idx = pp * 256 + threadIdx.x, rr = idx >> 6, cc = idx & 63;
      t[rr][cc] = Wsani[(size_t)(b0 + rr) * 1024 + coloff + a0 + cc];
    }
    __syncthreads();
    for (int pp = 0; pp < 16; ++pp) {
      int idx = pp * 256 + threadIdx.x, rr = idx >> 6, cc = idx & 63;
      float f = t[cc][rr];
      unsigned short hi = f2b(f);
      size_t o = (size_t)mat * 262144 + (size_t)(a0 + rr) * 512 + b0 + cc;
      Phi[o] = hi;
      Plo[o] = f2b(f - b2f(hi));
    }
    return;
  }
  if (blockIdx.x == 1024) {
    int tt = threadIdx.x;
    beta[tt] = bsani[tt];
    beta[tt + 256] = bsani[tt + 256];
    return;
  }
  int i = blockIdx.x * 256 + threadIdx.x;  // float4 index, total 262144
  if (i < 65536 || i >= 196608) {
    const float* src = (i < 65536) ? Win : Wout;
    unsigned short* dst = (i < 65536) ? dWin : dWout;
    int off = (i < 65536) ? i : i - 196608;
    floatx4 v = *(const floatx4*)(src + (size_t)off * 4);
    uint2 u;
    u.x = (unsigned)f2b(v.x) | ((unsigned)f2b(v.y) << 16);
    u.y = (unsigned)f2b(v.z) | ((unsigned)f2b(v.w) << 16);
    *(uint2*)(dst + (size_t)off * 4) = u;
  } else {
    int off = i - 65536;
    floatx4 v = *(const floatx4*)(Wsani + (size_t)off * 4);
    float f[4] = {v.x, v.y, v.z, v.w};
    unsigned short hb[4], lb[4];
#pragma unroll
    for (int k = 0; k < 4; ++k) {
      hb[k] = f2b(f[k]);
      lb[k] = f2b(f[k] - b2f(hb[k]));
    }
    uint2 h, l;
    h.x = hb[0] | ((unsigned)hb[1] << 16); h.y = hb[2] | ((unsigned)hb[3] << 16);
    l.x = lb[0] | ((unsigned)lb[1] << 16); l.y = lb[2] | ((unsigned)lb[3] << 16);
    *(uint2*)(dBcat1 + (size_t)off * 4) = h;
    *(uint2*)(dWsLo + (size_t)off * 4) = l;
  }
}

// ---- coefficient chain (FUSED): see round 15/16 (unchanged, bit-identical). ----
__global__ __launch_bounds__(256) void k_coef(const unsigned short* __restrict__ Phi,
                                              const unsigned short* __restrict__ Plo,
                                              unsigned short* __restrict__ PhiOut,
                                              unsigned short* __restrict__ PloOut,
                                              const unsigned short* __restrict__ WsHi,
                                              const unsigned short* __restrict__ WsLo,
                                              int m,
                                              unsigned short* __restrict__ BcatOut,
                                              const float* __restrict__ WsF,
                                              const float* __restrict__ bF,
                                              const float* __restrict__ bprev,
                                              float* __restrict__ bout,
                                              int nemb,
                                              const float* __restrict__ table,
                                              const int* __restrict__ labels,
                                              const unsigned short* __restrict__ Win_b,
                                              const float* __restrict__ b_in,
                                              unsigned short* __restrict__ xt,
                                              unsigned short* __restrict__ outs0) {
  __shared__ unsigned short lds[24576];   // 48 KB, shared by all branches
  const int ngemm = (m + 2) * 32;
  const int tid = threadIdx.x;

  if ((int)blockIdx.x >= ngemm + 128) {
    // ---- emb branch: x_t = bf16(emb @ W_in^T + b_in); outs[0] = x_t[0] ----
    const int ebid = blockIdx.x - (ngemm + 128);   // 0..nemb-1
    unsigned short* As = lds;                       // 64 x LDA (4608 shorts)
    unsigned short* Bs = lds + 4608;                // 128 x LDA (9216 shorts)
    int mtile = ebid >> 2, ntile = ebid & 3;
    int m0 = mtile * 64, n0 = ntile * 128;
    int lane = tid & 63, wave = tid >> 6, wm = wave >> 1, wn = wave & 1;
    floatx4 acc[2][4] = {};
    for (int k0 = 0; k0 < 512; k0 += 64) {
      stageA_emb(As, table, labels, m0, k0, tid);
      stageB(Bs, Win_b + (size_t)n0 * 512 + k0, 512, tid);
      __syncthreads();
      gemm_core24(As, Bs, acc, wm, wn, lane);
      __syncthreads();
    }
    int rb = lane & 15, rg = (lane >> 4) * 4;
#pragma unroll
    for (int i = 0; i < 2; ++i)
#pragma unroll
      for (int j = 0; j < 4; ++j) {
        int col = n0 + wn * 64 + j * 16 + rb;
        float bv = b_in[col];
#pragma unroll
        for (int reg = 0; reg < 4; ++reg) {
          int mm = m0 + wm * 32 + i * 16 + rg + reg;
          int n = mm >> 6, l = mm & 63;
          unsigned short v = f2b(acc[i][j][reg] + bv);
          xt[((size_t)l * NB + n) * HD + col] = v;
          if (l == 0) outs0[(size_t)n * HD + col] = v;
        }
      }
    return;
  }

  if ((int)blockIdx.x >= ngemm) {
    const int bb = blockIdx.x - ngemm;
    const int w = tid >> 6, lane2 = tid & 63;
    const int i = bb * 4 + w;
    float p = 0.f;
    for (int k = lane2; k < 512; k += 64)
      p += (WsF[(size_t)i * 1024 + k] + WsF[(size_t)i * 1024 + 512 + k]) * bprev[k];
#pragma unroll
    for (int off = 32; off > 0; off >>= 1) p += __shfl_down(p, off, 64);
    if (lane2 == 0) bout[i] = p + bF[i];
    return;
  }

  // ---- coef GEMM branch ----
  unsigned short* const A0 = lds;
  unsigned short* const A1 = lds + 4096;
  unsigned short* const B0 = lds + 8192;
  unsigned short* const B1 = lds + 16384;
  const int j = blockIdx.x >> 5, tile = blockIdx.x & 31;
  const int k0r = (tile >> 2) * 64, n0 = (tile & 3) * 128;
  const int lane = tid & 63, wave = tid >> 6, wm = wave >> 1, wn = wave & 1;
  const int rr_ = tid >> 3;
  const int kcs = (((tid & 7) ^ ((tid >> 3) & 7))) * 8;  // swizzled source column
  const int t_first = (j <= m) ? 0 : 1;
  const int nterms = ((j <= m) ? 1 : 0) + ((j >= 1) ? 1 : 0);
  const int nsteps = nterms * 24;         // 3 hi/lo passes x 8 t0-steps per term

  floatx4 acc[2][4] = {};

#define STAGE_C(Ab, Bb, u)                                                           \
  { int term_ = t_first + (((u) >= 24) ? 1 : 0);                                     \
    int v_ = ((u) >> 3) % 3;                                                         \
    int t0_ = ((u) & 7) * 64;                                                        \
    const unsigned short* As_ = ((v_ == 2) ? Plo : Phi)                              \
        + (size_t)(term_ ? (j - 1) : j) * 262144 + (size_t)k0r * 512 + t0_;          \
    const unsigned short* Bs_ = ((v_ == 1) ? WsLo : WsHi)                            \
        + (size_t)n0 * 1024 + (term_ ? 0 : 512) + t0_;                               \
    unsigned short* lA = (Ab) + (tid >> 6) * 512;                                    \
    unsigned short* lB = (Bb) + (tid >> 6) * 512;                                    \
    gl_lds16(As_ + (size_t)rr_ * 512 + kcs, lA);                                     \
    gl_lds16(As_ + (size_t)(rr_ + 32) * 512 + kcs, lA + 2048);                       \
    gl_lds16(Bs_ + (size_t)rr_ * 1024 + kcs, lB);                                    \
    gl_lds16(Bs_ + (size_t)(rr_ + 32) * 1024 + kcs, lB + 2048);                      \
    gl_lds16(Bs_ + (size_t)(rr_ + 64) * 1024 + kcs, lB + 4096);                      \
    gl_lds16(Bs_ + (size_t)(rr_ + 96) * 1024 + kcs, lB + 6144); }

  STAGE_C(A0, B0, 0)
  __syncthreads();
  for (int u = 0; u < nsteps; u += 2) {
    if (u + 1 < nsteps) STAGE_C(A1, B1, u + 1)
    gemm_core64s(A0, B0, acc, wm, wn, lane);
    __syncthreads();
    if (u + 2 < nsteps) STAGE_C(A0, B0, u + 2)
    gemm_core64s(A1, B1, acc, wm, wn, lane);
    __syncthreads();
  }
#undef STAGE_C

  unsigned short* CtT = lds;             // [128][72] (9216 shorts <= 24576)
  const int rb = lane & 15, rg = (lane >> 4) * 4;
#pragma unroll
  for (int i = 0; i < 2; ++i)
#pragma unroll
    for (int jj = 0; jj < 4; ++jj) {
      int colL = wn * 64 + jj * 16 + rb;     // 0..127 local (= Bcat row)
      int col = n0 + colL;
#pragma unroll
      for (int reg = 0; reg < 4; ++reg) {
        int row = wm * 32 + i * 16 + rg + reg;
        float f = acc[i][jj][reg];
        unsigned short hi = f2b(f);
        size_t o = (size_t)j * 262144 + (size_t)(k0r + row) * 512 + col;
        PhiOut[o] = hi;
        PloOut[o] = f2b(f - b2f(hi));
        CtT[colL * 72 + row] = hi;
      }
    }
  __syncthreads();
  const int rr2 = m + 1;
  const int ldB2 = (rr2 + 1) * 512;
  const int q = rr2 - j;
  const int rowi = tid >> 1, half = tid & 1;   // 256 thr = 128 rows x 2 halves
  unsigned short* dB = BcatOut + (size_t)(n0 + rowi) * ldB2 + q * 512 + k0r + half * 32;
  const unsigned short* sB = &CtT[rowi * 72 + half * 32];
#pragma unroll
  for (int c = 0; c < 4; ++c)
    *(uint4*)(dB + c * 8) = *(const uint4*)(sB + c * 8);
}

// ---- phase 2a (j<=8): PAIRED step -- one block = full 128-row slab x 128 cols.
//      B panel staged ONCE per K-step for both row-halves (1.5x traffic cut,
//      2x MFMA per barrier). Same K-order per element -> bit-identical. ----
__global__ __launch_bounds__(256) void k_step2(const unsigned short* __restrict__ src,
                                               unsigned short* __restrict__ dst,
                                               unsigned short* __restrict__ outs,
                                               const unsigned short* __restrict__ Bcat,
                                               const float* __restrict__ beta,
                                               int L_prev, int m, int nmain, int g) {
  __shared__ unsigned short lds[32768];   // A0[8192] B0[8192] A1[8192] B1[8192] = 64 KB
  unsigned short* const A0 = lds;
  unsigned short* const B0 = lds + 8192;
  unsigned short* const A1 = lds + 16384;
  unsigned short* const B1 = lds + 24576;
  const int tid = threadIdx.x, bid = blockIdx.x;
  const int mainWG = 16 * g;   // 8 XCDs x g slabs x 2 n-panels
  int r, s, n0;
  if (bid < mainWG) {
    const int xcd = bid & 7, w = bid >> 3;
    const int sgrp = xcd >> 1, ngrp = xcd & 1;
    const int s_rel = sgrp * g + (w >> 1);
    if (s_rel >= nmain) return;                    // uniform exit (pre-barrier)
    n0 = (ngrp * 2 + (w & 1)) * 128;
    r = m; s = L_prev + m + s_rel;
  } else {
    const int db = bid - mainWG;
    r = 1 + (db >> 2);
    n0 = (db & 3) * 128;
    s = L_prev + r;
  }
  const int ldB = (r + 1) * 512;
  const unsigned short* Bp = Bcat + (size_t)262144 * (((r - 1) * (r + 2)) >> 1);
  const unsigned short* abase = src + (size_t)(s - r) * NH;     // full slab
  const float* bet = beta + (size_t)(r - 1) * 512;
  const int nk = (r + 1) * 8;
  const int lane = tid & 63, wave = tid >> 6, wm = wave >> 1, wn = wave & 1;
  const int rr_ = tid >> 3;
  const int kcs = (((tid & 7) ^ ((tid >> 3) & 7))) * 8;

  floatx4 acc[4][4] = {};

#define STAGE2(Ab, Bb, kcol)                                                         \
  { int q_ = (kcol) >> 9, ac_ = (kcol) & 511;                                        \
    const unsigned short* a0_ = abase + (size_t)q_ * NH + ac_;                       \
    unsigned short* lA = (Ab) + (tid >> 6) * 512;                                    \
    unsigned short* lB = (Bb) + (tid >> 6) * 512;                                    \
    gl_lds16(a0_ + (size_t)rr_ * HD + kcs, lA);                                      \
    gl_lds16(a0_ + (size_t)(rr_ + 32) * HD + kcs, lA + 2048);                        \
    gl_lds16(a0_ + (size_t)(rr_ + 64) * HD + kcs, lA + 4096);                        \
    gl_lds16(a0_ + (size_t)(rr_ + 96) * HD + kcs, lA + 6144);                        \
    gl_lds16(Bp + (size_t)(n0 + rr_) * ldB + (kcol) + kcs, lB);                      \
    gl_lds16(Bp + (size_t)(n0 + rr_ + 32) * ldB + (kcol) + kcs, lB + 2048);          \
    gl_lds16(Bp + (size_t)(n0 + rr_ + 64) * ldB + (kcol) + kcs, lB + 4096);          \
    gl_lds16(Bp + (size_t)(n0 + rr_ + 96) * ldB + (kcol) + kcs, lB + 6144); }

  STAGE2(A0, B0, 0)
  __syncthreads();
  for (int k = 0; k < nk; k += 2) {
    if (k + 1 < nk) STAGE2(A1, B1, (k + 1) * 64)
    gemm_core128s(A0, B0, acc, wm, wn, lane);
    __syncthreads();
    if (k + 2 < nk) STAGE2(A0, B0, (k + 2) * 64)
    gemm_core128s(A1, B1, acc, wm, wn, lane);
    __syncthreads();
  }
#undef STAGE2

  // ---- epilogue: stage C (128x128 bf16) in LDS, then full-line stores ----
  unsigned short* Ct = lds;            // 128 x LDC = 17408 shorts <= 32768
  const int rbc = lane & 15, rg = (lane >> 4) * 4;
#pragma unroll
  for (int i = 0; i < 4; ++i)
#pragma unroll
    for (int j = 0; j < 4; ++j) {
      int col = wn * 64 + j * 16 + rbc;            // 0..127 local
      float bv = bet[n0 + col];
#pragma unroll
      for (int reg = 0; reg < 4; ++reg) {
        int row = wm * 64 + i * 16 + rg + reg;     // 0..127 local
        Ct[row * LDC + col] = f2b(acc[i][j][reg] + bv);
      }
    }
  __syncthreads();
  const bool wdst = (r == m);
  const bool wout = (r < m) || (s == L_prev + m);  // outs[li] = h(li,li)
  unsigned short* d1 = dst  + (size_t)s * NH + n0;
  unsigned short* d2 = outs + (size_t)s * NH + n0;
  const int lrow = tid >> 4, lcol = (tid & 15) * 8;  // 16 thr x 16B = 256B/row
#pragma unroll
  for (int sweep = 0; sweep < 8; ++sweep) {
    int row = sweep * 16 + lrow;
    uint4 v = *(const uint4*)&Ct[row * LDC + lcol];
    if (wdst) *(uint4*)(d1 + (size_t)row * HD + lcol) = v;
    if (wout) *(uint4*)(d2 + (size_t)row * HD + lcol) = v;
  }
}

// ---- phase 2b (j>=9): proven round-16 step kernel, unchanged. ----
__global__ __launch_bounds__(256) void k_step(const unsigned short* __restrict__ src,
                                              unsigned short* __restrict__ dst,
                                              unsigned short* __restrict__ outs,
                                              const unsigned short* __restrict__ Bcat,
                                              const float* __restrict__ beta,
                                              int L_prev, int m, int nmain, int g) {
  __shared__ unsigned short lds[24576];   // A0[4096] A1[4096] B0[8192] B1[8192] = 48 KB
  unsigned short* const A0 = lds;
  unsigned short* const A1 = lds + 4096;
  unsigned short* const B0 = lds + 8192;
  unsigned short* const B1 = lds + 16384;
  const int tid = threadIdx.x, bid = blockIdx.x;
  const int mainWG = 32 * g;   // 8 XCDs x g slabs x 4 (2 nb0 x 2 n-panels)
  int r, s, nb0, n0;
  if (bid < mainWG) {
    const int xcd = bid & 7, w = bid >> 3;        // dispatch round-robin -> XCD
    const int sgrp = xcd >> 1, ngrp = xcd & 1;
    const int s_rel = sgrp * g + (w >> 2);
    if (s_rel >= nmain) return;                    // uniform block exit (pre-barrier)
    const int sub2 = w & 3;
    nb0 = (sub2 >> 1) * 64;
    n0 = (ngrp * 2 + (sub2 & 1)) * 128;
    r = m; s = L_prev + m + s_rel;
  } else {
    const int db = bid - mainWG;
    r = 1 + (db >> 3);
    const int sub = db & 7;
    nb0 = (sub >> 2) * 64; n0 = (sub & 3) * 128;
    s = L_prev + r;
  }
  const int ldB = (r + 1) * 512;
  const unsigned short* Bp = Bcat + (size_t)262144 * (((r - 1) * (r + 2)) >> 1);
  const unsigned short* abase = src + (size_t)(s - r) * NH + (size_t)nb0 * HD;
  const float* bet = beta + (size_t)(r - 1) * 512;
  const int nk = (r + 1) * 8;        // always even (16,24,32,40)
  const int lane = tid & 63, wave = tid >> 6, wm = wave >> 1, wn = wave & 1;
  const int rr_ = tid >> 3;
  const int kcs = (((tid & 7) ^ ((tid >> 3) & 7))) * 8;  // swizzled source column

  floatx4 acc[2][4] = {};

#define STAGE(Ab, Bb, kcol)                                                          \
  { int q_ = (kcol) >> 9, ac_ = (kcol) & 511;                                        \
    const unsigned short* a0_ = abase + (size_t)q_ * NH + ac_;                       \
    unsigned short* lA = (Ab) + (tid >> 6) * 512;                                    \
    unsigned short* lB = (Bb) + (tid >> 6) * 512;                                    \
    gl_lds16(a0_ + (size_t)rr_ * HD + kcs, lA);                                      \
    gl_lds16(a0_ + (size_t)(rr_ + 32) * HD + kcs, lA + 2048);                        \
    gl_lds16(Bp + (size_t)(n0 + rr_) * ldB + (kcol) + kcs, lB);                      \
    gl_lds16(Bp + (size_t)(n0 + rr_ + 32) * ldB + (kcol) + kcs, lB + 2048);          \
    gl_lds16(Bp + (size_t)(n0 + rr_ + 64) * ldB + (kcol) + kcs, lB + 4096);          \
    gl_lds16(Bp + (size_t)(n0 + rr_ + 96) * ldB + (kcol) + kcs, lB + 6144); }

  STAGE(A0, B0, 0)
  __syncthreads();                     // drain prologue loads
  for (int k = 0; k < nk; k += 2) {
    if (k + 1 < nk) STAGE(A1, B1, (k + 1) * 64)   // prefetch hides under MFMA
    gemm_core64s(A0, B0, acc, wm, wn, lane);
    __syncthreads();                               // drain prefetch + WAR-protect A0/B0
    if (k + 2 < nk) STAGE(A0, B0, (k + 2) * 64)
    gemm_core64s(A1, B1, acc, wm, wn, lane);
    __syncthreads();
  }
#undef STAGE

  unsigned short* Ct = lds;            // 64 x LDC = 8704 shorts <= 24576
  const int rbc = lane & 15, rg = (lane >> 4) * 4;
#pragma unroll
  for (int i = 0; i < 2; ++i)
#pragma unroll
    for (int j = 0; j < 4; ++j) {
      int col = wn * 64 + j * 16 + rbc;            // 0..127 local
      float bv = bet[n0 + col];
#pragma unroll
      for (int reg = 0; reg < 4; ++reg) {
        int row = wm * 32 + i * 16 + rg + reg;     // 0..63 local
        Ct[row * LDC + col] = f2b(acc[i][j][reg] + bv);
      }
    }
  __syncthreads();
  const bool wdst = (r == m);
  const bool wout = (r < m) || (s == L_prev + m);  // outs[li] = h(li,li)
  unsigned short* d1 = dst  + (size_t)s * NH + (size_t)nb0 * HD + n0;
  unsigned short* d2 = outs + (size_t)s * NH + (size_t)nb0 * HD + n0;
  const int lrow = tid >> 4, lcol = (tid & 15) * 8;  // 16 thr x 16B = 256B/row
#pragma unroll
  for (int sweep = 0; sweep < 4; ++sweep) {
    int row = sweep * 16 + lrow;
    uint4 v = *(const uint4*)&Ct[row * LDC + lcol];
    if (wdst) *(uint4*)(d1 + (size_t)row * HD + lcol) = v;
    if (wout) *(uint4*)(d2 + (size_t)row * HD + lcol) = v;
  }
}

// ---- phase 3 (TEMPLATE): Y = outs_flat @ W_out^T + b_out (fp32 out). ----
__global__ __launch_bounds__(256) void k_gemm_out(const unsigned short* __restrict__ outs,
                                                  const unsigned short* __restrict__ Wb,
                                                  const float* __restrict__ bias,
                                                  float* __restrict__ Y) {
  __shared__ unsigned short lds[24576];
  unsigned short* const A0 = lds;
  unsigned short* const A1 = lds + 4096;
  unsigned short* const B0 = lds + 8192;
  unsigned short* const B1 = lds + 16384;
  const int tid = threadIdx.x;
  const int mtile = blockIdx.x >> 2, ntile = blockIdx.x & 3;
  const int m0 = mtile * 64, n0 = ntile * 128;
  const int lane = tid & 63, wave = tid >> 6, wm = wave >> 1, wn = wave & 1;
  const int rr_ = tid >> 3;
  const int kcs = (((tid & 7) ^ ((tid >> 3) & 7))) * 8;
  const unsigned short* abase = outs + (size_t)m0 * 512;
  const unsigned short* Bp = Wb + (size_t)n0 * 512;

  floatx4 acc[2][4] = {};

#define STAGE_O(Ab, Bb, kcol)                                                        \
  { unsigned short* lA = (Ab) + (tid >> 6) * 512;                                    \
    unsigned short* lB = (Bb) + (tid >> 6) * 512;                                    \
    gl_lds16(abase + (size_t)rr_ * 512 + (kcol) + kcs, lA);                          \
    gl_lds16(abase + (size_t)(rr_ + 32) * 512 + (kcol) + kcs, lA + 2048);            \
    gl_lds16(Bp + (size_t)rr_ * 512 + (kcol) + kcs, lB);                             \
    gl_lds16(Bp + (size_t)(rr_ + 32) * 512 + (kcol) + kcs, lB + 2048);               \
    gl_lds16(Bp + (size_t)(rr_ + 64) * 512 + (kcol) + kcs, lB + 4096);               \
    gl_lds16(Bp + (size_t)(rr_ + 96) * 512 + (kcol) + kcs, lB + 6144); }

  STAGE_O(A0, B0, 0)
  __syncthreads();
  for (int k = 0; k < 8; k += 2) {
    if (k + 1 < 8) STAGE_O(A1, B1, (k + 1) * 64)
    gemm_core64s(A0, B0, acc, wm, wn, lane);
    __syncthreads();
    if (k + 2 < 8) STAGE_O(A0, B0, (k + 2) * 64)
    gemm_core64s(A1, B1, acc, wm, wn, lane);
    __syncthreads();
  }
#undef STAGE_O

  float* Ctf = (float*)lds;            // 64 x LDCF x 4B = 33792 B <= 49152
  const int rbc = lane & 15, rg = (lane >> 4) * 4;
#pragma unroll
  for (int i = 0; i < 2; ++i)
#pragma unroll
    for (int j = 0; j < 4; ++j) {
      int col = wn * 64 + j * 16 + rbc;
      float bv = bias[n0 + col];
#pragma unroll
      for (int reg = 0; reg < 4; ++reg) {
        int row = wm * 32 + i * 16 + rg + reg;
        Ctf[row * LDCF + col] = acc[i][j][reg] + bv;
      }
    }
  __syncthreads();
  const int lrow = tid >> 5, lc = (tid & 31) * 4;   // 32 thr x 16B = 512B/row
#pragma unroll
  for (int sweep = 0; sweep < 8; ++sweep) {
    int row = sweep * 8 + lrow;
    uint4 v = *(const uint4*)&Ctf[row * LDCF + lc];
    *(uint4*)&Y[(size_t)(m0 + row) * 512 + n0 + lc] = v;
  }
}

// ---- loss: per n, column-softmax over 64 consecutive Y rows, dot with emb ----
__global__ __launch_bounds__(256) void k_loss(const float* __restrict__ Y,
                                              const float* __restrict__ table,
                                              const int* __restrict__ labels,
                                              float* __restrict__ partials) {
  int n = blockIdx.x, tid = threadIdx.x;
  float total = 0.f;
#pragma unroll
  for (int e2 = 0; e2 < 2; ++e2) {
    int e = e2 * 256 + tid;
    float mx = -1e30f;
    for (int l = 0; l < 64; ++l)
      mx = fmaxf(mx, Y[(size_t)(n * 64 + l) * 512 + e]);
    float se = 0.f;
    for (int l = 0; l < 64; ++l)
      se += expf(Y[(size_t)(n * 64 + l) * 512 + e] - mx);
    float lse = mx + logf(se);
    for (int l = 0; l < 64; ++l) {
      float embv = table[(size_t)labels[n * 64 + l] * ED + e];
      total += embv * (Y[(size_t)(n * 64 + l) * 512 + e] - lse);
    }
  }
  __shared__ float red[256];
  red[tid] = total;
  __syncthreads();
  for (int s2 = 128; s2 > 0; s2 >>= 1) {
    if (tid < s2) red[tid] += red[tid + s2];
    __syncthreads();
  }
  if (tid == 0) partials[n] = red[0];
}

__global__ void k_final(const float* __restrict__ partials, float* __restrict__ out) {
  if (threadIdx.x == 0) {
    double s = 0.0;
    for (int i = 0; i < 128; ++i) s += (double)partials[i];
    out[0] = (float)(-s / 65536.0);
  }
}

extern "C" void kernel_launch(void* const* d_in, const int* in_sizes, int n_in,
                              void* d_out, int out_size, void* d_ws, size_t ws_size,
                              hipStream_t stream) {
  const int*   labels = (const int*)d_in[0];
  const float* table  = (const float*)d_in[1];
  const float* W_in   = (const float*)d_in[2];
  const float* b_in   = (const float*)d_in[3];
  const float* W_sani = (const float*)d_in[4];
  const float* b_sani = (const float*)d_in[5];
  const float* W_out  = (const float*)d_in[6];
  const float* b_out  = (const float*)d_in[7];

  char* ws = (char*)d_ws;
  unsigned short* Win_b  = (unsigned short*)(ws + OFF_WIN);
  unsigned short* Wout_b = (unsigned short*)(ws + OFF_WOUT);
  unsigned short* xt     = (unsigned short*)(ws + OFF_XT);
  unsigned short* lvl0   = (unsigned short*)(ws + OFF_LVL0);
  unsigned short* lvl1   = (unsigned short*)(ws + OFF_LVL1);
  unsigned short* outs   = (unsigned short*)(ws + OFF_OUTS);
  unsigned short* PhiA   = (unsigned short*)(ws + OFF_PHA);
  unsigned short* PloA   = (unsigned short*)(ws + OFF_PLA);
  unsigned short* PhiB   = (unsigned short*)(ws + OFF_PHB);
  unsigned short* PloB   = (unsigned short*)(ws + OFF_PLB);
  unsigned short* Bcat   = (unsigned short*)(ws + OFF_BCAT);
  float*          beta   = (float*)(ws + OFF_BETA);
  float*          parts  = (float*)(ws + OFF_PART);
  unsigned short* WsLo   = (unsigned short*)(ws + OFF_WSLO);
  float*          Y      = (float*)(ws + OFF_Y);

  // Launch 1: cvtw (1024) + beta_1 copy (1) + trW (128)
  k_phase1<<<1153, 256, 0, stream>>>(W_in, W_sani, W_out, Win_b, Bcat, WsLo, Wout_b,
                                     b_sani, beta, PhiA, PloA);

  // Launch 2: coef1 (96) + bias beta_2 (128) + emb GEMM (512, independent, overlaps)
  k_coef<<< 96 + 128 + 512, 256, 0, stream>>>(PhiA, PloA, PhiB, PloB, Bcat, WsLo, 1,
                                        Bcat + 524288, W_sani, b_sani,
                                        beta, beta + 512, 512,
                                        table, labels, Win_b, b_in, xt, outs);
  k_coef<<<128 + 128, 256, 0, stream>>>(PhiB, PloB, PhiA, PloA, Bcat, WsLo, 2,
                                        Bcat + 1310720, W_sani, b_sani,
                                        beta + 512, beta + 1024, 0,
                                        table, labels, Win_b, b_in, xt, outs);
  k_coef<<<160 + 128, 256, 0, stream>>>(PhiA, PloA, PhiB, PloB, Bcat, WsLo, 3,
                                        Bcat + 2359296, W_sani, b_sani,
                                        beta + 1024, beta + 1536, 0,
                                        table, labels, Win_b, b_in, xt, outs);

  // 16 multi-level steps (15 x m=4, 1 x m=3); paired kernel for big grids (j<=8)
  const unsigned short* srcp = xt;
  for (int j = 1; j <= 16; ++j) {
    int L_prev = 4 * (j - 1);
    int m = (j == 16) ? 3 : 4;
    int nmain = 64 - (L_prev + m);
    int g = (nmain + 3) >> 2;          // slabs per s-group (4 s-groups)
    unsigned short* dstp = ((j - 1) & 1) ? lvl1 : lvl0;
    if (j <= 8)
      k_step2<<<16 * g + (m - 1) * 4, 256, 0, stream>>>(srcp, dstp, outs, Bcat, beta,
                                                        L_prev, m, nmain, g);
    else
      k_step<<<32 * g + (m - 1) * 8, 256, 0, stream>>>(srcp, dstp, outs, Bcat, beta,
                                                       L_prev, m, nmain, g);
    srcp = dstp;
  }

  k_gemm_out<<<512, 256, 0, stream>>>(outs, Wout_b, b_out, Y);
  k_loss<<<128, 256, 0, stream>>>(Y, table, labels, parts);
  k_final<<<1, 64, 0, stream>>>(parts, (float*)d_out);
}

// Round 19
// 555.773 us; speedup vs baseline: 1.0454x; 1.0440x over previous
//
#include <hip/hip_runtime.h>
#include <hip/hip_bf16.h>

typedef __attribute__((ext_vector_type(8))) short short8;
typedef __attribute__((ext_vector_type(4))) float floatx4;

#define NB 128      // batch N
#define LS 64       // seq L
#define HD 512      // hidden H
#define ED 512      // embed E
#define NH 65536    // NB*HD elements per s-slab
#define LDA 72      // LDS tile stride for reg-staged kernels (64 + 8 pad)
#define LDC 136     // LDS C-tile stride bf16 (128 + 8 pad)
#define LDCF 132    // LDS C-tile stride f32 (128 + 4 pad)

// ws layout (byte offsets)
#define OFF_WIN    0ull          // W_in bf16   [512*512]
#define OFF_WOUT   524288ull     // W_out bf16  [512*512]
#define OFF_XT     1048576ull    // x_t bf16    [64][128][512]  (= level 0)
#define OFF_LVL0   9437184ull    // level ping  bf16 [64][128][512]
#define OFF_LVL1   17825792ull   // level pong  bf16 [64][128][512]
#define OFF_OUTS   26214400ull   // outs bf16   [64][128][512]
#define OFF_PHA    34603008ull   // P hi ping  bf16 (5x 512x512, 2.62 MB)
#define OFF_PLA    37224448ull   // P lo ping
#define OFF_PHB    39845888ull   // P hi pong
#define OFF_PLB    42467328ull   // P lo pong
#define OFF_BCAT   45088768ull   // Bcat_1..4 bf16 concat (7 MB); Bcat_1 == WsHi
#define OFF_BETA   52428800ull   // beta_1..4 f32 [4][512]
#define OFF_PART   52436992ull   // partials f32 [128]
#define OFF_WSLO   52437504ull   // W_sani lo bf16 [512*1024] (1 MB)
#define OFF_Y      OFF_LVL0      // Y f32 [8192][512] aliases lvl bufs after recurrence

static __device__ __forceinline__ unsigned short f2b(float f) {
  unsigned u = __float_as_uint(f);
  u += 0x7fffu + ((u >> 16) & 1u);   // round-to-nearest-even
  return (unsigned short)(u >> 16);
}
static __device__ __forceinline__ float b2f(unsigned short h) {
  return __uint_as_float(((unsigned)h) << 16);
}

// async global -> LDS, 16B per lane; LDS dest = wave-uniform base + lane*16
static __device__ __forceinline__ void gl_lds16(const unsigned short* g, unsigned short* l) {
  __builtin_amdgcn_global_load_lds(
      (const __attribute__((address_space(1))) void*)g,
      (__attribute__((address_space(3))) void*)l, 16, 0, 0);
}

// load 8 consecutive f32, produce bf16x8 packed (hi only; used for emb gather)
static __device__ __forceinline__ uint4 cvt8hi(const float* s) {
  floatx4 f0 = *(const floatx4*)s;
  floatx4 f1 = *(const floatx4*)(s + 4);
  float f[8] = {f0.x, f0.y, f0.z, f0.w, f1.x, f1.y, f1.z, f1.w};
  unsigned short b[8];
#pragma unroll
  for (int k = 0; k < 8; ++k) b[k] = f2b(f[k]);
  uint4 u;
  u.x = b[0] | ((unsigned)b[1] << 16); u.y = b[2] | ((unsigned)b[3] << 16);
  u.z = b[4] | ((unsigned)b[5] << 16); u.w = b[6] | ((unsigned)b[7] << 16);
  return u;
}

// ---- padded-LDS GEMM core (emb branch): BM=64, BN=128, 4 waves 2x2 ----
__device__ __forceinline__ void gemm_core24(const unsigned short* As, const unsigned short* Bs,
                                            floatx4 acc[2][4], int wm, int wn, int lane) {
  const int rb = lane & 15;
  const int kg = (lane >> 4) * 8;
#pragma unroll
  for (int kk = 0; kk < 64; kk += 32) {
    short8 a[2], b[4];
#pragma unroll
    for (int i = 0; i < 2; ++i)
      a[i] = *(const short8*)&As[(wm * 32 + i * 16 + rb) * LDA + kk + kg];
#pragma unroll
    for (int j = 0; j < 4; ++j)
      b[j] = *(const short8*)&Bs[(wn * 64 + j * 16 + rb) * LDA + kk + kg];
#pragma unroll
    for (int i = 0; i < 2; ++i)
#pragma unroll
      for (int j = 0; j < 4; ++j)
        acc[i][j] = __builtin_amdgcn_mfma_f32_16x16x32_bf16(a[i], b[j], acc[i][j], 0, 0, 0);
  }
}

// ---- UNPADDED stride-64 core with XOR bank swizzle (gload_lds-staged kernels). ----
__device__ __forceinline__ void gemm_core64s(const unsigned short* As, const unsigned short* Bs,
                                             floatx4 acc[2][4], int wm, int wn, int lane) {
  const int rb = lane & 15;
  const int kg = (lane >> 4) * 8;
  const int xv = (rb & 7) * 8;       // XOR swizzle, units of 8 shorts (16B)
#pragma unroll
  for (int kk = 0; kk < 64; kk += 32) {
    const int co = (kk + kg) ^ xv;   // kk+kg is a multiple of 8 -> pure slot XOR
    short8 a[2], b[4];
#pragma unroll
    for (int i = 0; i < 2; ++i)
      a[i] = *(const short8*)&As[(wm * 32 + i * 16 + rb) * 64 + co];
#pragma unroll
    for (int j = 0; j < 4; ++j)
      b[j] = *(const short8*)&Bs[(wn * 64 + j * 16 + rb) * 64 + co];
#pragma unroll
    for (int i = 0; i < 2; ++i)
#pragma unroll
      for (int j = 0; j < 4; ++j)
        acc[i][j] = __builtin_amdgcn_mfma_f32_16x16x32_bf16(a[i], b[j], acc[i][j], 0, 0, 0);
  }
}

__device__ __forceinline__ void stageA_emb(unsigned short* As, const float* table,
                                           const int* labels, int m0, int k0, int tid) {
  int r = tid >> 3, kc = (tid & 7) * 8;
#pragma unroll
  for (int p = 0; p < 2; ++p) {
    int row = r + p * 32;
    const float* s = table + (size_t)labels[m0 + row] * ED + k0 + kc;
    *(uint4*)&As[row * LDA + kc] = cvt8hi(s);
  }
}

__device__ __forceinline__ void stageB(unsigned short* Bs, const unsigned short* src, int ldB, int tid) {
  int r = tid >> 3, kc = (tid & 7) * 8;
#pragma unroll
  for (int p = 0; p < 4; ++p)
    *(uint4*)&Bs[(r + p * 32) * LDA + kc] = *(const uint4*)(src + (size_t)(r + p * 32) * ldB + kc);
}

// ---- LAUNCH 1 (fused): blocks 0..1023 cvtw; 1024 beta_1 copy; 1025..1152 trW. ----
__global__ __launch_bounds__(256) void k_phase1(const float* __restrict__ Win,
                                                const float* __restrict__ Wsani,
                                                const float* __restrict__ Wout,
                                                unsigned short* __restrict__ dWin,
                                                unsigned short* __restrict__ dBcat1,
                                                unsigned short* __restrict__ dWsLo,
                                                unsigned short* __restrict__ dWout,
                                                const float* __restrict__ bsani,
                                                float* __restrict__ beta,
                                                unsigned short* __restrict__ Phi,
                                                unsigned short* __restrict__ Plo) {
  __shared__ float t[64][65];
  if (blockIdx.x >= 1025) {
    int bidt = blockIdx.x - 1025;
    int mat = bidt >> 6, tile = bidt & 63;
    int a0 = (tile >> 3) * 64, b0 = (tile & 7) * 64;
    int coloff = (mat == 0) ? 512 : 0;   // P_{1,0}=W2^T, P_{1,1}=W1^T
    for (int pp = 0; pp < 16; ++pp) {
      int idx = pp * 256 + threadIdx.x, rr = idx >> 6, cc = idx & 63;
      t[rr][cc] = Wsani[(size_t)(b0 + rr) * 1024 + coloff + a0 + cc];
    }
    __syncthreads();
    for (int pp = 0; pp < 16; ++pp) {
      int idx = pp * 256 + threadIdx.x, rr = idx >> 6, cc = idx & 63;
      float f = t[cc][rr];
      unsigned short hi = f2b(f);
      size_t o = (size_t)mat * 262144 + (size_t)(a0 + rr) * 512 + b0 + cc;
      Phi[o] = hi;
      Plo[o] = f2b(f - b2f(hi));
    }
    return;
  }
  if (blockIdx.x == 1024) {
    int tt = threadIdx.x;
    beta[tt] = bsani[tt];
    beta[tt + 256] = bsani[tt + 256];
    return;
  }
  int i = blockIdx.x * 256 + threadIdx.x;  // float4 index, total 262144
  if (i < 65536 || i >= 196608) {
    const float* src = (i < 65536) ? Win : Wout;
    unsigned short* dst = (i < 65536) ? dWin : dWout;
    int off = (i < 65536) ? i : i - 196608;
    floatx4 v = *(const floatx4*)(src + (size_t)off * 4);
    uint2 u;
    u.x = (unsigned)f2b(v.x) | ((unsigned)f2b(v.y) << 16);
    u.y = (unsigned)f2b(v.z) | ((unsigned)f2b(v.w) << 16);
    *(uint2*)(dst + (size_t)off * 4) = u;
  } else {
    int off = i - 65536;
    floatx4 v = *(const floatx4*)(Wsani + (size_t)off * 4);
    float f[4] = {v.x, v.y, v.z, v.w};
    unsigned short hb[4], lb[4];
#pragma unroll
    for (int k = 0; k < 4; ++k) {
      hb[k] = f2b(f[k]);
      lb[k] = f2b(f[k] - b2f(hb[k]));
    }
    uint2 h, l;
    h.x = hb[0] | ((unsigned)hb[1] << 16); h.y = hb[2] | ((unsigned)hb[3] << 16);
    l.x = lb[0] | ((unsigned)lb[1] << 16); l.y = lb[2] | ((unsigned)lb[3] << 16);
    *(uint2*)(dBcat1 + (size_t)off * 4) = h;
    *(uint2*)(dWsLo + (size_t)off * 4) = l;
  }
}

// ---- coefficient chain (FUSED): GEMM blocks compute P_{m+1,j} = P_{m,j}@W2 + P_{m,j-1}@W1
//      (hi/lo bf16 in AND out), write Phi/Plo AND transposed Bcat_{m+1} tile.
//      +128 blocks: beta_{m+1} (wave64 reduce). +nemb blocks (m=1 launch only):
//      the x_t embedding GEMM (independent of the coef chain; overlaps it). ----
__global__ __launch_bounds__(256) void k_coef(const unsigned short* __restrict__ Phi,
                                              const unsigned short* __restrict__ Plo,
                                              unsigned short* __restrict__ PhiOut,
                                              unsigned short* __restrict__ PloOut,
                                              const unsigned short* __restrict__ WsHi,
                                              const unsigned short* __restrict__ WsLo,
                                              int m,
                                              unsigned short* __restrict__ BcatOut,
                                              const float* __restrict__ WsF,
                                              const float* __restrict__ bF,
                                              const float* __restrict__ bprev,
                                              float* __restrict__ bout,
                                              int nemb,
                                              const float* __restrict__ table,
                                              const int* __restrict__ labels,
                                              const unsigned short* __restrict__ Win_b,
                                              const float* __restrict__ b_in,
                                              unsigned short* __restrict__ xt,
                                              unsigned short* __restrict__ outs0) {
  __shared__ unsigned short lds[24576];   // 48 KB, shared by all branches
  const int ngemm = (m + 2) * 32;
  const int tid = threadIdx.x;

  if ((int)blockIdx.x >= ngemm + 128) {
    // ---- emb branch: x_t = bf16(emb @ W_in^T + b_in); outs[0] = x_t[0] ----
    const int ebid = blockIdx.x - (ngemm + 128);   // 0..nemb-1
    unsigned short* As = lds;                       // 64 x LDA (4608 shorts)
    unsigned short* Bs = lds + 4608;                // 128 x LDA (9216 shorts)
    int mtile = ebid >> 2, ntile = ebid & 3;
    int m0 = mtile * 64, n0 = ntile * 128;
    int lane = tid & 63, wave = tid >> 6, wm = wave >> 1, wn = wave & 1;
    floatx4 acc[2][4] = {};
    for (int k0 = 0; k0 < 512; k0 += 64) {
      stageA_emb(As, table, labels, m0, k0, tid);
      stageB(Bs, Win_b + (size_t)n0 * 512 + k0, 512, tid);
      __syncthreads();
      gemm_core24(As, Bs, acc, wm, wn, lane);
      __syncthreads();
    }
    int rb = lane & 15, rg = (lane >> 4) * 4;
#pragma unroll
    for (int i = 0; i < 2; ++i)
#pragma unroll
      for (int j = 0; j < 4; ++j) {
        int col = n0 + wn * 64 + j * 16 + rb;
        float bv = b_in[col];
#pragma unroll
        for (int reg = 0; reg < 4; ++reg) {
          int mm = m0 + wm * 32 + i * 16 + rg + reg;
          int n = mm >> 6, l = mm & 63;
          unsigned short v = f2b(acc[i][j][reg] + bv);
          xt[((size_t)l * NB + n) * HD + col] = v;
          if (l == 0) outs0[(size_t)n * HD + col] = v;
        }
      }
    return;
  }

  if ((int)blockIdx.x >= ngemm) {
    const int bb = blockIdx.x - ngemm;
    const int w = tid >> 6, lane2 = tid & 63;
    const int i = bb * 4 + w;
    float p = 0.f;
    for (int k = lane2; k < 512; k += 64)
      p += (WsF[(size_t)i * 1024 + k] + WsF[(size_t)i * 1024 + 512 + k]) * bprev[k];
#pragma unroll
    for (int off = 32; off > 0; off >>= 1) p += __shfl_down(p, off, 64);
    if (lane2 == 0) bout[i] = p + bF[i];
    return;
  }

  // ---- coef GEMM branch ----
  unsigned short* const A0 = lds;
  unsigned short* const A1 = lds + 4096;
  unsigned short* const B0 = lds + 8192;
  unsigned short* const B1 = lds + 16384;
  const int j = blockIdx.x >> 5, tile = blockIdx.x & 31;
  const int k0r = (tile >> 2) * 64, n0 = (tile & 3) * 128;
  const int lane = tid & 63, wave = tid >> 6, wm = wave >> 1, wn = wave & 1;
  const int rr_ = tid >> 3;
  const int kcs = (((tid & 7) ^ ((tid >> 3) & 7))) * 8;  // swizzled source column
  const int t_first = (j <= m) ? 0 : 1;
  const int nterms = ((j <= m) ? 1 : 0) + ((j >= 1) ? 1 : 0);
  const int nsteps = nterms * 24;         // 3 hi/lo passes x 8 t0-steps per term

  floatx4 acc[2][4] = {};

#define STAGE_C(Ab, Bb, u)                                                           \
  { int term_ = t_first + (((u) >= 24) ? 1 : 0);                                     \
    int v_ = ((u) >> 3) % 3;                                                         \
    int t0_ = ((u) & 7) * 64;                                                        \
    const unsigned short* As_ = ((v_ == 2) ? Plo : Phi)                              \
        + (size_t)(term_ ? (j - 1) : j) * 262144 + (size_t)k0r * 512 + t0_;          \
    const unsigned short* Bs_ = ((v_ == 1) ? WsLo : WsHi)                            \
        + (size_t)n0 * 1024 + (term_ ? 0 : 512) + t0_;                               \
    unsigned short* lA = (Ab) + (tid >> 6) * 512;                                    \
    unsigned short* lB = (Bb) + (tid >> 6) * 512;                                    \
    gl_lds16(As_ + (size_t)rr_ * 512 + kcs, lA);                                     \
    gl_lds16(As_ + (size_t)(rr_ + 32) * 512 + kcs, lA + 2048);                       \
    gl_lds16(Bs_ + (size_t)rr_ * 1024 + kcs, lB);                                    \
    gl_lds16(Bs_ + (size_t)(rr_ + 32) * 1024 + kcs, lB + 2048);                      \
    gl_lds16(Bs_ + (size_t)(rr_ + 64) * 1024 + kcs, lB + 4096);                      \
    gl_lds16(Bs_ + (size_t)(rr_ + 96) * 1024 + kcs, lB + 6144); }

  STAGE_C(A0, B0, 0)
  __syncthreads();
  for (int u = 0; u < nsteps; u += 2) {
    if (u + 1 < nsteps) STAGE_C(A1, B1, u + 1)
    gemm_core64s(A0, B0, acc, wm, wn, lane);
    __syncthreads();
    if (u + 2 < nsteps) STAGE_C(A0, B0, u + 2)
    gemm_core64s(A1, B1, acc, wm, wn, lane);
    __syncthreads();
  }
#undef STAGE_C

  unsigned short* CtT = lds;             // [128][72] (9216 shorts <= 24576)
  const int rb = lane & 15, rg = (lane >> 4) * 4;
#pragma unroll
  for (int i = 0; i < 2; ++i)
#pragma unroll
    for (int jj = 0; jj < 4; ++jj) {
      int colL = wn * 64 + jj * 16 + rb;     // 0..127 local (= Bcat row)
      int col = n0 + colL;
#pragma unroll
      for (int reg = 0; reg < 4; ++reg) {
        int row = wm * 32 + i * 16 + rg + reg;
        float f = acc[i][jj][reg];
        unsigned short hi = f2b(f);
        size_t o = (size_t)j * 262144 + (size_t)(k0r + row) * 512 + col;
        PhiOut[o] = hi;
        PloOut[o] = f2b(f - b2f(hi));
        CtT[colL * 72 + row] = hi;
      }
    }
  __syncthreads();
  const int rr2 = m + 1;
  const int ldB2 = (rr2 + 1) * 512;
  const int q = rr2 - j;
  const int rowi = tid >> 1, half = tid & 1;   // 256 thr = 128 rows x 2 halves
  unsigned short* dB = BcatOut + (size_t)(n0 + rowi) * ldB2 + q * 512 + k0r + half * 32;
  const unsigned short* sB = &CtT[rowi * 72 + half * 32];
#pragma unroll
  for (int c = 0; c < 4; ++c)
    *(uint4*)(dB + c * 8) = *(const uint4*)(sB + c * 8);
}

// ---- phase 2: one multi-level step (template; m=4 sweet spot, L2-fit working set). ----
__global__ __launch_bounds__(256) void k_step(const unsigned short* __restrict__ src,
                                              unsigned short* __restrict__ dst,
                                              unsigned short* __restrict__ outs,
                                              const unsigned short* __restrict__ Bcat,
                                              const float* __restrict__ beta,
                                              int L_prev, int m, int nmain, int g) {
  __shared__ unsigned short lds[24576];   // A0[4096] A1[4096] B0[8192] B1[8192] = 48 KB
  unsigned short* const A0 = lds;
  unsigned short* const A1 = lds + 4096;
  unsigned short* const B0 = lds + 8192;
  unsigned short* const B1 = lds + 16384;
  const int tid = threadIdx.x, bid = blockIdx.x;
  const int mainWG = 32 * g;   // 8 XCDs x g slabs x 4 (2 nb0 x 2 n-panels)
  int r, s, nb0, n0;
  if (bid < mainWG) {
    const int xcd = bid & 7, w = bid >> 3;        // dispatch round-robin -> XCD
    const int sgrp = xcd >> 1, ngrp = xcd & 1;
    const int s_rel = sgrp * g + (w >> 2);
    if (s_rel >= nmain) return;                    // uniform block exit (pre-barrier)
    const int sub2 = w & 3;
    nb0 = (sub2 >> 1) * 64;
    n0 = (ngrp * 2 + (sub2 & 1)) * 128;
    r = m; s = L_prev + m + s_rel;
  } else {
    const int db = bid - mainWG;
    r = 1 + (db >> 3);
    const int sub = db & 7;
    nb0 = (sub >> 2) * 64; n0 = (sub & 3) * 128;
    s = L_prev + r;
  }
  const int ldB = (r + 1) * 512;
  const unsigned short* Bp = Bcat + (size_t)262144 * (((r - 1) * (r + 2)) >> 1);
  const unsigned short* abase = src + (size_t)(s - r) * NH + (size_t)nb0 * HD;
  const float* bet = beta + (size_t)(r - 1) * 512;
  const int nk = (r + 1) * 8;        // always even (16,24,32,40)
  const int lane = tid & 63, wave = tid >> 6, wm = wave >> 1, wn = wave & 1;
  const int rr_ = tid >> 3;
  const int kcs = (((tid & 7) ^ ((tid >> 3) & 7))) * 8;  // swizzled source column

  floatx4 acc[2][4] = {};

#define STAGE(Ab, Bb, kcol)                                                          \
  { int q_ = (kcol) >> 9, ac_ = (kcol) & 511;                                        \
    const unsigned short* a0_ = abase + (size_t)q_ * NH + ac_;                       \
    unsigned short* lA = (Ab) + (tid >> 6) * 512;                                    \
    unsigned short* lB = (Bb) + (tid >> 6) * 512;                                    \
    gl_lds16(a0_ + (size_t)rr_ * HD + kcs, lA);                                      \
    gl_lds16(a0_ + (size_t)(rr_ + 32) * HD + kcs, lA + 2048);                        \
    gl_lds16(Bp + (size_t)(n0 + rr_) * ldB + (kcol) + kcs, lB);                      \
    gl_lds16(Bp + (size_t)(n0 + rr_ + 32) * ldB + (kcol) + kcs, lB + 2048);          \
    gl_lds16(Bp + (size_t)(n0 + rr_ + 64) * ldB + (kcol) + kcs, lB + 4096);          \
    gl_lds16(Bp + (size_t)(n0 + rr_ + 96) * ldB + (kcol) + kcs, lB + 6144); }

  STAGE(A0, B0, 0)
  __syncthreads();                     // drain prologue loads
  for (int k = 0; k < nk; k += 2) {
    if (k + 1 < nk) STAGE(A1, B1, (k + 1) * 64)   // prefetch hides under MFMA
    gemm_core64s(A0, B0, acc, wm, wn, lane);
    __syncthreads();                               // drain prefetch + WAR-protect A0/B0
    if (k + 2 < nk) STAGE(A0, B0, (k + 2) * 64)
    gemm_core64s(A1, B1, acc, wm, wn, lane);
    __syncthreads();
  }
#undef STAGE

  // ---- epilogue: stage C (64x128 bf16) in LDS, then full-line stores ----
  unsigned short* Ct = lds;            // 64 x LDC = 8704 shorts <= 24576
  const int rbc = lane & 15, rg = (lane >> 4) * 4;
#pragma unroll
  for (int i = 0; i < 2; ++i)
#pragma unroll
    for (int j = 0; j < 4; ++j) {
      int col = wn * 64 + j * 16 + rbc;            // 0..127 local
      float bv = bet[n0 + col];
#pragma unroll
      for (int reg = 0; reg < 4; ++reg) {
        int row = wm * 32 + i * 16 + rg + reg;     // 0..63 local
        Ct[row * LDC + col] = f2b(acc[i][j][reg] + bv);
      }
    }
  __syncthreads();
  const bool wdst = (r == m);
  const bool wout = (r < m) || (s == L_prev + m);  // outs[li] = h(li,li)
  unsigned short* d1 = dst  + (size_t)s * NH + (size_t)nb0 * HD + n0;
  unsigned short* d2 = outs + (size_t)s * NH + (size_t)nb0 * HD + n0;
  const int lrow = tid >> 4, lcol = (tid & 15) * 8;  // 16 thr x 16B = 256B/row
#pragma unroll
  for (int sweep = 0; sweep < 4; ++sweep) {
    int row = sweep * 16 + lrow;
    uint4 v = *(const uint4*)&Ct[row * LDC + lcol];
    if (wdst) *(uint4*)(d1 + (size_t)row * HD + lcol) = v;
    if (wout) *(uint4*)(d2 + (size_t)row * HD + lcol) = v;
  }
}

// ---- phase 3 (TEMPLATE): Y = outs_flat @ W_out^T + b_out (fp32 out). ----
__global__ __launch_bounds__(256) void k_gemm_out(const unsigned short* __restrict__ outs,
                                                  const unsigned short* __restrict__ Wb,
                                                  const float* __restrict__ bias,
                                                  float* __restrict__ Y) {
  __shared__ unsigned short lds[24576];
  unsigned short* const A0 = lds;
  unsigned short* const A1 = lds + 4096;
  unsigned short* const B0 = lds + 8192;
  unsigned short* const B1 = lds + 16384;
  const int tid = threadIdx.x;
  const int mtile = blockIdx.x >> 2, ntile = blockIdx.x & 3;
  const int m0 = mtile * 64, n0 = ntile * 128;
  const int lane = tid & 63, wave = tid >> 6, wm = wave >> 1, wn = wave & 1;
  const int rr_ = tid >> 3;
  const int kcs = (((tid & 7) ^ ((tid >> 3) & 7))) * 8;
  const unsigned short* abase = outs + (size_t)m0 * 512;
  const unsigned short* Bp = Wb + (size_t)n0 * 512;

  floatx4 acc[2][4] = {};

#define STAGE_O(Ab, Bb, kcol)                                                        \
  { unsigned short* lA = (Ab) + (tid >> 6) * 512;                                    \
    unsigned short* lB = (Bb) + (tid >> 6) * 512;                                    \
    gl_lds16(abase + (size_t)rr_ * 512 + (kcol) + kcs, lA);                          \
    gl_lds16(abase + (size_t)(rr_ + 32) * 512 + (kcol) + kcs, lA + 2048);            \
    gl_lds16(Bp + (size_t)rr_ * 512 + (kcol) + kcs, lB);                             \
    gl_lds16(Bp + (size_t)(rr_ + 32) * 512 + (kcol) + kcs, lB + 2048);               \
    gl_lds16(Bp + (size_t)(rr_ + 64) * 512 + (kcol) + kcs, lB + 4096);               \
    gl_lds16(Bp + (size_t)(rr_ + 96) * 512 + (kcol) + kcs, lB + 6144); }

  STAGE_O(A0, B0, 0)
  __syncthreads();
  for (int k = 0; k < 8; k += 2) {
    if (k + 1 < 8) STAGE_O(A1, B1, (k + 1) * 64)
    gemm_core64s(A0, B0, acc, wm, wn, lane);
    __syncthreads();
    if (k + 2 < 8) STAGE_O(A0, B0, (k + 2) * 64)
    gemm_core64s(A1, B1, acc, wm, wn, lane);
    __syncthreads();
  }
#undef STAGE_O

  // ---- epilogue: stage C (64x128 f32) in LDS, then full-line stores ----
  float* Ctf = (float*)lds;            // 64 x LDCF x 4B = 33792 B <= 49152
  const int rbc = lane & 15, rg = (lane >> 4) * 4;
#pragma unroll
  for (int i = 0; i < 2; ++i)
#pragma unroll
    for (int j = 0; j < 4; ++j) {
      int col = wn * 64 + j * 16 + rbc;
      float bv = bias[n0 + col];
#pragma unroll
      for (int reg = 0; reg < 4; ++reg) {
        int row = wm * 32 + i * 16 + rg + reg;
        Ctf[row * LDCF + col] = acc[i][j][reg] + bv;
      }
    }
  __syncthreads();
  const int lrow = tid >> 5, lc = (tid & 31) * 4;   // 32 thr x 16B = 512B/row
#pragma unroll
  for (int sweep = 0; sweep < 8; ++sweep) {
    int row = sweep * 8 + lrow;
    uint4 v = *(const uint4*)&Ctf[row * LDCF + lc];
    *(uint4*)&Y[(size_t)(m0 + row) * 512 + n0 + lc] = v;
  }
}

// ---- loss: per n, column-softmax over 64 consecutive Y rows, dot with emb ----
__global__ __launch_bounds__(256) void k_loss(const float* __restrict__ Y,
                                              const float* __restrict__ table,
                                              const int* __restrict__ labels,
                                              float* __restrict__ partials) {
  int n = blockIdx.x, tid = threadIdx.x;
  float total = 0.f;
#pragma unroll
  for (int e2 = 0; e2 < 2; ++e2) {
    int e = e2 * 256 + tid;
    float mx = -1e30f;
    for (int l = 0; l < 64; ++l)
      mx = fmaxf(mx, Y[(size_t)(n * 64 + l) * 512 + e]);
    float se = 0.f;
    for (int l = 0; l < 64; ++l)
      se += expf(Y[(size_t)(n * 64 + l) * 512 + e] - mx);
    float lse = mx + logf(se);
    for (int l = 0; l < 64; ++l) {
      float embv = table[(size_t)labels[n * 64 + l] * ED + e];
      total += embv * (Y[(size_t)(n * 64 + l) * 512 + e] - lse);
    }
  }
  __shared__ float red[256];
  red[tid] = total;
  __syncthreads();
  for (int s2 = 128; s2 > 0; s2 >>= 1) {
    if (tid < s2) red[tid] += red[tid + s2];
    __syncthreads();
  }
  if (tid == 0) partials[n] = red[0];
}

__global__ void k_final(const float* __restrict__ partials, float* __restrict__ out) {
  if (threadIdx.x == 0) {
    double s = 0.0;
    for (int i = 0; i < 128; ++i) s += (double)partials[i];
    out[0] = (float)(-s / 65536.0);
  }
}

extern "C" void kernel_launch(void* const* d_in, const int* in_sizes, int n_in,
                              void* d_out, int out_size, void* d_ws, size_t ws_size,
                              hipStream_t stream) {
  const int*   labels = (const int*)d_in[0];
  const float* table  = (const float*)d_in[1];
  const float* W_in   = (const float*)d_in[2];
  const float* b_in   = (const float*)d_in[3];
  const float* W_sani = (const float*)d_in[4];
  const float* b_sani = (const float*)d_in[5];
  const float* W_out  = (const float*)d_in[6];
  const float* b_out  = (const float*)d_in[7];

  char* ws = (char*)d_ws;
  unsigned short* Win_b  = (unsigned short*)(ws + OFF_WIN);
  unsigned short* Wout_b = (unsigned short*)(ws + OFF_WOUT);
  unsigned short* xt     = (unsigned short*)(ws + OFF_XT);
  unsigned short* lvl0   = (unsigned short*)(ws + OFF_LVL0);
  unsigned short* lvl1   = (unsigned short*)(ws + OFF_LVL1);
  unsigned short* outs   = (unsigned short*)(ws + OFF_OUTS);
  unsigned short* PhiA   = (unsigned short*)(ws + OFF_PHA);
  unsigned short* PloA   = (unsigned short*)(ws + OFF_PLA);
  unsigned short* PhiB   = (unsigned short*)(ws + OFF_PHB);
  unsigned short* PloB   = (unsigned short*)(ws + OFF_PLB);
  unsigned short* Bcat   = (unsigned short*)(ws + OFF_BCAT);
  float*          beta   = (float*)(ws + OFF_BETA);
  float*          parts  = (float*)(ws + OFF_PART);
  unsigned short* WsLo   = (unsigned short*)(ws + OFF_WSLO);
  float*          Y      = (float*)(ws + OFF_Y);

  // Launch 1: cvtw (1024) + beta_1 copy (1) + trW (128)
  k_phase1<<<1153, 256, 0, stream>>>(W_in, W_sani, W_out, Win_b, Bcat, WsLo, Wout_b,
                                     b_sani, beta, PhiA, PloA);

  // Launch 2: coef1 (96) + bias beta_2 (128) + emb GEMM (512, independent, overlaps)
  k_coef<<< 96 + 128 + 512, 256, 0, stream>>>(PhiA, PloA, PhiB, PloB, Bcat, WsLo, 1,
                                        Bcat + 524288, W_sani, b_sani,
                                        beta, beta + 512, 512,
                                        table, labels, Win_b, b_in, xt, outs);
  k_coef<<<128 + 128, 256, 0, stream>>>(PhiB, PloB, PhiA, PloA, Bcat, WsLo, 2,
                                        Bcat + 1310720, W_sani, b_sani,
                                        beta + 512, beta + 1024, 0,
                                        table, labels, Win_b, b_in, xt, outs);
  k_coef<<<160 + 128, 256, 0, stream>>>(PhiA, PloA, PhiB, PloB, Bcat, WsLo, 3,
                                        Bcat + 2359296, W_sani, b_sani,
                                        beta + 1024, beta + 1536, 0,
                                        table, labels, Win_b, b_in, xt, outs);

  // 16 multi-level steps (15 x m=4, 1 x m=3)
  const unsigned short* srcp = xt;
  for (int j = 1; j <= 16; ++j) {
    int L_prev = 4 * (j - 1);
    int m = (j == 16) ? 3 : 4;
    int nmain = 64 - (L_prev + m);
    int g = (nmain + 3) >> 2;          // slabs per s-group (4 s-groups)
    unsigned short* dstp = ((j - 1) & 1) ? lvl1 : lvl0;
    k_step<<<32 * g + (m - 1) * 8, 256, 0, stream>>>(srcp, dstp, outs, Bcat, beta,
                                                     L_prev, m, nmain, g);
    srcp = dstp;
  }

  k_gemm_out<<<512, 256, 0, stream>>>(outs, Wout_b, b_out, Y);
  k_loss<<<128, 256, 0, stream>>>(Y, table, labels, parts);
  k_final<<<1, 64, 0, stream>>>(parts, (float*)d_out);
}

// Round 20
// 554.646 us; speedup vs baseline: 1.0475x; 1.0020x over previous
//
#include <hip/hip_runtime.h>
#include <hip/hip_bf16.h>

typedef __attribute__((ext_vector_type(8))) short short8;
typedef __attribute__((ext_vector_type(4))) float floatx4;

#define NB 128      // batch N
#define LS 64       // seq L
#define HD 512      // hidden H
#define ED 512      // embed E
#define NH 65536    // NB*HD elements per s-slab
#define LDA 72      // LDS tile stride for reg-staged kernels (64 + 8 pad)
#define LDC 136     // LDS C-tile stride bf16 (128 + 8 pad)
#define LDCF 132    // LDS C-tile stride f32 (128 + 4 pad)

// ws layout (byte offsets)
#define OFF_WIN    0ull          // W_in bf16   [512*512]
#define OFF_WOUT   524288ull     // W_out bf16  [512*512]
#define OFF_XT     1048576ull    // x_t bf16    [64][128][512]  (= level 0)
#define OFF_LVL0   9437184ull    // level ping  bf16 [64][128][512]
#define OFF_LVL1   17825792ull   // level pong  bf16 [64][128][512]
#define OFF_OUTS   26214400ull   // outs bf16   [64][128][512]
#define OFF_PHA    34603008ull   // P hi ping  bf16 (5x 512x512, 2.62 MB)
#define OFF_PLA    37224448ull   // P lo ping
#define OFF_PHB    39845888ull   // P hi pong
#define OFF_PLB    42467328ull   // P lo pong
#define OFF_BCAT   45088768ull   // Bcat_1..4 bf16 concat (7 MB); Bcat_1 == WsHi
#define OFF_BETA   52428800ull   // beta_1..4 f32 [4][512]
#define OFF_PART   52436992ull   // partials f32 [128]
#define OFF_WSLO   52437504ull   // W_sani lo bf16 [512*1024] (1 MB)
#define OFF_Y      OFF_LVL0      // Y f32 [8192][512] aliases lvl bufs after recurrence

static __device__ __forceinline__ unsigned short f2b(float f) {
  unsigned u = __float_as_uint(f);
  u += 0x7fffu + ((u >> 16) & 1u);   // round-to-nearest-even
  return (unsigned short)(u >> 16);
}
static __device__ __forceinline__ float b2f(unsigned short h) {
  return __uint_as_float(((unsigned)h) << 16);
}

// async global -> LDS, 16B per lane; LDS dest = wave-uniform base + lane*16
static __device__ __forceinline__ void gl_lds16(const unsigned short* g, unsigned short* l) {
  __builtin_amdgcn_global_load_lds(
      (const __attribute__((address_space(1))) void*)g,
      (__attribute__((address_space(3))) void*)l, 16, 0, 0);
}

// load 8 consecutive f32, produce bf16x8 packed (hi only; used for emb gather)
static __device__ __forceinline__ uint4 cvt8hi(const float* s) {
  floatx4 f0 = *(const floatx4*)s;
  floatx4 f1 = *(const floatx4*)(s + 4);
  float f[8] = {f0.x, f0.y, f0.z, f0.w, f1.x, f1.y, f1.z, f1.w};
  unsigned short b[8];
#pragma unroll
  for (int k = 0; k < 8; ++k) b[k] = f2b(f[k]);
  uint4 u;
  u.x = b[0] | ((unsigned)b[1] << 16); u.y = b[2] | ((unsigned)b[3] << 16);
  u.z = b[4] | ((unsigned)b[5] << 16); u.w = b[6] | ((unsigned)b[7] << 16);
  return u;
}

// ---- padded-LDS GEMM core (emb branch): BM=64, BN=128, 4 waves 2x2 ----
__device__ __forceinline__ void gemm_core24(const unsigned short* As, const unsigned short* Bs,
                                            floatx4 acc[2][4], int wm, int wn, int lane) {
  const int rb = lane & 15;
  const int kg = (lane >> 4) * 8;
#pragma unroll
  for (int kk = 0; kk < 64; kk += 32) {
    short8 a[2], b[4];
#pragma unroll
    for (int i = 0; i < 2; ++i)
      a[i] = *(const short8*)&As[(wm * 32 + i * 16 + rb) * LDA + kk + kg];
#pragma unroll
    for (int j = 0; j < 4; ++j)
      b[j] = *(const short8*)&Bs[(wn * 64 + j * 16 + rb) * LDA + kk + kg];
#pragma unroll
    for (int i = 0; i < 2; ++i)
#pragma unroll
      for (int j = 0; j < 4; ++j)
        acc[i][j] = __builtin_amdgcn_mfma_f32_16x16x32_bf16(a[i], b[j], acc[i][j], 0, 0, 0);
  }
}

// ---- UNPADDED stride-64 core with XOR bank swizzle (gload_lds-staged kernels). ----
__device__ __forceinline__ void gemm_core64s(const unsigned short* As, const unsigned short* Bs,
                                             floatx4 acc[2][4], int wm, int wn, int lane) {
  const int rb = lane & 15;
  const int kg = (lane >> 4) * 8;
  const int xv = (rb & 7) * 8;       // XOR swizzle, units of 8 shorts (16B)
#pragma unroll
  for (int kk = 0; kk < 64; kk += 32) {
    const int co = (kk + kg) ^ xv;   // kk+kg is a multiple of 8 -> pure slot XOR
    short8 a[2], b[4];
#pragma unroll
    for (int i = 0; i < 2; ++i)
      a[i] = *(const short8*)&As[(wm * 32 + i * 16 + rb) * 64 + co];
#pragma unroll
    for (int j = 0; j < 4; ++j)
      b[j] = *(const short8*)&Bs[(wn * 64 + j * 16 + rb) * 64 + co];
#pragma unroll
    for (int i = 0; i < 2; ++i)
#pragma unroll
      for (int j = 0; j < 4; ++j)
        acc[i][j] = __builtin_amdgcn_mfma_f32_16x16x32_bf16(a[i], b[j], acc[i][j], 0, 0, 0);
  }
}

__device__ __forceinline__ void stageA_emb(unsigned short* As, const float* table,
                                           const int* labels, int m0, int k0, int tid) {
  int r = tid >> 3, kc = (tid & 7) * 8;
#pragma unroll
  for (int p = 0; p < 2; ++p) {
    int row = r + p * 32;
    const float* s = table + (size_t)labels[m0 + row] * ED + k0 + kc;
    *(uint4*)&As[row * LDA + kc] = cvt8hi(s);
  }
}

__device__ __forceinline__ void stageB(unsigned short* Bs, const unsigned short* src, int ldB, int tid) {
  int r = tid >> 3, kc = (tid & 7) * 8;
#pragma unroll
  for (int p = 0; p < 4; ++p)
    *(uint4*)&Bs[(r + p * 32) * LDA + kc] = *(const uint4*)(src + (size_t)(r + p * 32) * ldB + kc);
}

// ---- LAUNCH 1 (fused): blocks 0..1023 cvtw; 1024 beta_1 copy; 1025..1152 trW. ----
__global__ __launch_bounds__(256) void k_phase1(const float* __restrict__ Win,
                                                const float* __restrict__ Wsani,
                                                const float* __restrict__ Wout,
                                                unsigned short* __restrict__ dWin,
                                                unsigned short* __restrict__ dBcat1,
                                                unsigned short* __restrict__ dWsLo,
                                                unsigned short* __restrict__ dWout,
                                                const float* __restrict__ bsani,
                                                float* __restrict__ beta,
                                                unsigned short* __restrict__ Phi,
                                                unsigned short* __restrict__ Plo) {
  __shared__ float t[64][65];
  if (blockIdx.x >= 1025) {
    int bidt = blockIdx.x - 1025;
    int mat = bidt >> 6, tile = bidt & 63;
    int a0 = (tile >> 3) * 64, b0 = (tile & 7) * 64;
    int coloff = (mat == 0) ? 512 : 0;   // P_{1,0}=W2^T, P_{1,1}=W1^T
    for (int pp = 0; pp < 16; ++pp) {
      int idx = pp * 256 + threadIdx.x, rr = idx >> 6, cc = idx & 63;
      t[rr][cc] = Wsani[(size_t)(b0 + rr) * 1024 + coloff + a0 + cc];
    }
    __syncthreads();
    for (int pp = 0; pp < 16; ++pp) {
      int idx = pp * 256 + threadIdx.x, rr = idx >> 6, cc = idx & 63;
      float f = t[cc][rr];
      unsigned short hi = f2b(f);
      size_t o = (size_t)mat * 262144 + (size_t)(a0 + rr) * 512 + b0 + cc;
      Phi[o] = hi;
      Plo[o] = f2b(f - b2f(hi));
    }
    return;
  }
  if (blockIdx.x == 1024) {
    int tt = threadIdx.x;
    beta[tt] = bsani[tt];
    beta[tt + 256] = bsani[tt + 256];
    return;
  }
  int i = blockIdx.x * 256 + threadIdx.x;  // float4 index, total 262144
  if (i < 65536 || i >= 196608) {
    const float* src = (i < 65536) ? Win : Wout;
    unsigned short* dst = (i < 65536) ? dWin : dWout;
    int off = (i < 65536) ? i : i - 196608;
    floatx4 v = *(const floatx4*)(src + (size_t)off * 4);
    uint2 u;
    u.x = (unsigned)f2b(v.x) | ((unsigned)f2b(v.y) << 16);
    u.y = (unsigned)f2b(v.z) | ((unsigned)f2b(v.w) << 16);
    *(uint2*)(dst + (size_t)off * 4) = u;
  } else {
    int off = i - 65536;
    floatx4 v = *(const floatx4*)(Wsani + (size_t)off * 4);
    float f[4] = {v.x, v.y, v.z, v.w};
    unsigned short hb[4], lb[4];
#pragma unroll
    for (int k = 0; k < 4; ++k) {
      hb[k] = f2b(f[k]);
      lb[k] = f2b(f[k] - b2f(hb[k]));
    }
    uint2 h, l;
    h.x = hb[0] | ((unsigned)hb[1] << 16); h.y = hb[2] | ((unsigned)hb[3] << 16);
    l.x = lb[0] | ((unsigned)lb[1] << 16); l.y = lb[2] | ((unsigned)lb[3] << 16);
    *(uint2*)(dBcat1 + (size_t)off * 4) = h;
    *(uint2*)(dWsLo + (size_t)off * 4) = l;
  }
}

// ---- coefficient chain (FUSED): GEMM blocks compute P_{m+1,j} = P_{m,j}@W2 + P_{m,j-1}@W1
//      (hi/lo bf16 in AND out), write Phi/Plo AND transposed Bcat_{m+1} tile.
//      +128 blocks: beta_{m+1} (wave64 reduce). +nemb blocks (m=1 launch only):
//      the x_t embedding GEMM (independent of the coef chain; overlaps it). ----
__global__ __launch_bounds__(256) void k_coef(const unsigned short* __restrict__ Phi,
                                              const unsigned short* __restrict__ Plo,
                                              unsigned short* __restrict__ PhiOut,
                                              unsigned short* __restrict__ PloOut,
                                              const unsigned short* __restrict__ WsHi,
                                              const unsigned short* __restrict__ WsLo,
                                              int m,
                                              unsigned short* __restrict__ BcatOut,
                                              const float* __restrict__ WsF,
                                              const float* __restrict__ bF,
                                              const float* __restrict__ bprev,
                                              float* __restrict__ bout,
                                              int nemb,
                                              const float* __restrict__ table,
                                              const int* __restrict__ labels,
                                              const unsigned short* __restrict__ Win_b,
                                              const float* __restrict__ b_in,
                                              unsigned short* __restrict__ xt,
                                              unsigned short* __restrict__ outs0) {
  __shared__ unsigned short lds[24576];   // 48 KB, shared by all branches
  const int ngemm = (m + 2) * 32;
  const int tid = threadIdx.x;

  if ((int)blockIdx.x >= ngemm + 128) {
    // ---- emb branch: x_t = bf16(emb @ W_in^T + b_in); outs[0] = x_t[0] ----
    const int ebid = blockIdx.x - (ngemm + 128);   // 0..nemb-1
    unsigned short* As = lds;                       // 64 x LDA (4608 shorts)
    unsigned short* Bs = lds + 4608;                // 128 x LDA (9216 shorts)
    int mtile = ebid >> 2, ntile = ebid & 3;
    int m0 = mtile * 64, n0 = ntile * 128;
    int lane = tid & 63, wave = tid >> 6, wm = wave >> 1, wn = wave & 1;
    floatx4 acc[2][4] = {};
    for (int k0 = 0; k0 < 512; k0 += 64) {
      stageA_emb(As, table, labels, m0, k0, tid);
      stageB(Bs, Win_b + (size_t)n0 * 512 + k0, 512, tid);
      __syncthreads();
      gemm_core24(As, Bs, acc, wm, wn, lane);
      __syncthreads();
    }
    int rb = lane & 15, rg = (lane >> 4) * 4;
#pragma unroll
    for (int i = 0; i < 2; ++i)
#pragma unroll
      for (int j = 0; j < 4; ++j) {
        int col = n0 + wn * 64 + j * 16 + rb;
        float bv = b_in[col];
#pragma unroll
        for (int reg = 0; reg < 4; ++reg) {
          int mm = m0 + wm * 32 + i * 16 + rg + reg;
          int n = mm >> 6, l = mm & 63;
          unsigned short v = f2b(acc[i][j][reg] + bv);
          xt[((size_t)l * NB + n) * HD + col] = v;
          if (l == 0) outs0[(size_t)n * HD + col] = v;
        }
      }
    return;
  }

  if ((int)blockIdx.x >= ngemm) {
    const int bb = blockIdx.x - ngemm;
    const int w = tid >> 6, lane2 = tid & 63;
    const int i = bb * 4 + w;
    float p = 0.f;
    for (int k = lane2; k < 512; k += 64)
      p += (WsF[(size_t)i * 1024 + k] + WsF[(size_t)i * 1024 + 512 + k]) * bprev[k];
#pragma unroll
    for (int off = 32; off > 0; off >>= 1) p += __shfl_down(p, off, 64);
    if (lane2 == 0) bout[i] = p + bF[i];
    return;
  }

  // ---- coef GEMM branch ----
  unsigned short* const A0 = lds;
  unsigned short* const A1 = lds + 4096;
  unsigned short* const B0 = lds + 8192;
  unsigned short* const B1 = lds + 16384;
  const int j = blockIdx.x >> 5, tile = blockIdx.x & 31;
  const int k0r = (tile >> 2) * 64, n0 = (tile & 3) * 128;
  const int lane = tid & 63, wave = tid >> 6, wm = wave >> 1, wn = wave & 1;
  const int rr_ = tid >> 3;
  const int kcs = (((tid & 7) ^ ((tid >> 3) & 7))) * 8;  // swizzled source column
  const int t_first = (j <= m) ? 0 : 1;
  const int nterms = ((j <= m) ? 1 : 0) + ((j >= 1) ? 1 : 0);
  const int nsteps = nterms * 24;         // 3 hi/lo passes x 8 t0-steps per term

  floatx4 acc[2][4] = {};

#define STAGE_C(Ab, Bb, u)                                                           \
  { int term_ = t_first + (((u) >= 24) ? 1 : 0);                                     \
    int v_ = ((u) >> 3) % 3;                                                         \
    int t0_ = ((u) & 7) * 64;                                                        \
    const unsigned short* As_ = ((v_ == 2) ? Plo : Phi)                              \
        + (size_t)(term_ ? (j - 1) : j) * 262144 + (size_t)k0r * 512 + t0_;          \
    const unsigned short* Bs_ = ((v_ == 1) ? WsLo : WsHi)                            \
        + (size_t)n0 * 1024 + (term_ ? 0 : 512) + t0_;                               \
    unsigned short* lA = (Ab) + (tid >> 6) * 512;                                    \
    unsigned short* lB = (Bb) + (tid >> 6) * 512;                                    \
    gl_lds16(As_ + (size_t)rr_ * 512 + kcs, lA);                                     \
    gl_lds16(As_ + (size_t)(rr_ + 32) * 512 + kcs, lA + 2048);                       \
    gl_lds16(Bs_ + (size_t)rr_ * 1024 + kcs, lB);                                    \
    gl_lds16(Bs_ + (size_t)(rr_ + 32) * 1024 + kcs, lB + 2048);                      \
    gl_lds16(Bs_ + (size_t)(rr_ + 64) * 1024 + kcs, lB + 4096);                      \
    gl_lds16(Bs_ + (size_t)(rr_ + 96) * 1024 + kcs, lB + 6144); }

  STAGE_C(A0, B0, 0)
  __syncthreads();
  for (int u = 0; u < nsteps; u += 2) {
    if (u + 1 < nsteps) STAGE_C(A1, B1, u + 1)
    gemm_core64s(A0, B0, acc, wm, wn, lane);
    __syncthreads();
    if (u + 2 < nsteps) STAGE_C(A0, B0, u + 2)
    gemm_core64s(A1, B1, acc, wm, wn, lane);
    __syncthreads();
  }
#undef STAGE_C

  unsigned short* CtT = lds;             // [128][72] (9216 shorts <= 24576)
  const int rb = lane & 15, rg = (lane >> 4) * 4;
#pragma unroll
  for (int i = 0; i < 2; ++i)
#pragma unroll
    for (int jj = 0; jj < 4; ++jj) {
      int colL = wn * 64 + jj * 16 + rb;     // 0..127 local (= Bcat row)
      int col = n0 + colL;
#pragma unroll
      for (int reg = 0; reg < 4; ++reg) {
        int row = wm * 32 + i * 16 + rg + reg;
        float f = acc[i][jj][reg];
        unsigned short hi = f2b(f);
        size_t o = (size_t)j * 262144 + (size_t)(k0r + row) * 512 + col;
        PhiOut[o] = hi;
        PloOut[o] = f2b(f - b2f(hi));
        CtT[colL * 72 + row] = hi;
      }
    }
  __syncthreads();
  const int rr2 = m + 1;
  const int ldB2 = (rr2 + 1) * 512;
  const int q = rr2 - j;
  const int rowi = tid >> 1, half = tid & 1;   // 256 thr = 128 rows x 2 halves
  unsigned short* dB = BcatOut + (size_t)(n0 + rowi) * ldB2 + q * 512 + k0r + half * 32;
  const unsigned short* sB = &CtT[rowi * 72 + half * 32];
#pragma unroll
  for (int c = 0; c < 4; ++c)
    *(uint4*)(dB + c * 8) = *(const uint4*)(sB + c * 8);
}

// ---- phase 2: one multi-level step (template; m=4 sweet spot, L2-fit working set). ----
__global__ __launch_bounds__(256) void k_step(const unsigned short* __restrict__ src,
                                              unsigned short* __restrict__ dst,
                                              unsigned short* __restrict__ outs,
                                              const unsigned short* __restrict__ Bcat,
                                              const float* __restrict__ beta,
                                              int L_prev, int m, int nmain, int g) {
  __shared__ unsigned short lds[24576];   // A0[4096] A1[4096] B0[8192] B1[8192] = 48 KB
  unsigned short* const A0 = lds;
  unsigned short* const A1 = lds + 4096;
  unsigned short* const B0 = lds + 8192;
  unsigned short* const B1 = lds + 16384;
  const int tid = threadIdx.x, bid = blockIdx.x;
  const int mainWG = 32 * g;   // 8 XCDs x g slabs x 4 (2 nb0 x 2 n-panels)
  int r, s, nb0, n0;
  if (bid < mainWG) {
    const int xcd = bid & 7, w = bid >> 3;        // dispatch round-robin -> XCD
    const int sgrp = xcd >> 1, ngrp = xcd & 1;
    const int s_rel = sgrp * g + (w >> 2);
    if (s_rel >= nmain) return;                    // uniform block exit (pre-barrier)
    const int sub2 = w & 3;
    nb0 = (sub2 >> 1) * 64;
    n0 = (ngrp * 2 + (sub2 & 1)) * 128;
    r = m; s = L_prev + m + s_rel;
  } else {
    const int db = bid - mainWG;
    r = 1 + (db >> 3);
    const int sub = db & 7;
    nb0 = (sub >> 2) * 64; n0 = (sub & 3) * 128;
    s = L_prev + r;
  }
  const int ldB = (r + 1) * 512;
  const unsigned short* Bp = Bcat + (size_t)262144 * (((r - 1) * (r + 2)) >> 1);
  const unsigned short* abase = src + (size_t)(s - r) * NH + (size_t)nb0 * HD;
  const float* bet = beta + (size_t)(r - 1) * 512;
  const int nk = (r + 1) * 8;        // always even (16,24,32,40)
  const int lane = tid & 63, wave = tid >> 6, wm = wave >> 1, wn = wave & 1;
  const int rr_ = tid >> 3;
  const int kcs = (((tid & 7) ^ ((tid >> 3) & 7))) * 8;  // swizzled source column

  floatx4 acc[2][4] = {};

#define STAGE(Ab, Bb, kcol)                                                          \
  { int q_ = (kcol) >> 9, ac_ = (kcol) & 511;                                        \
    const unsigned short* a0_ = abase + (size_t)q_ * NH + ac_;                       \
    unsigned short* lA = (Ab) + (tid >> 6) * 512;                                    \
    unsigned short* lB = (Bb) + (tid >> 6) * 512;                                    \
    gl_lds16(a0_ + (size_t)rr_ * HD + kcs, lA);                                      \
    gl_lds16(a0_ + (size_t)(rr_ + 32) * HD + kcs, lA + 2048);                        \
    gl_lds16(Bp + (size_t)(n0 + rr_) * ldB + (kcol) + kcs, lB);                      \
    gl_lds16(Bp + (size_t)(n0 + rr_ + 32) * ldB + (kcol) + kcs, lB + 2048);          \
    gl_lds16(Bp + (size_t)(n0 + rr_ + 64) * ldB + (kcol) + kcs, lB + 4096);          \
    gl_lds16(Bp + (size_t)(n0 + rr_ + 96) * ldB + (kcol) + kcs, lB + 6144); }

  STAGE(A0, B0, 0)
  __syncthreads();                     // drain prologue loads
  for (int k = 0; k < nk; k += 2) {
    if (k + 1 < nk) STAGE(A1, B1, (k + 1) * 64)   // prefetch hides under MFMA
    gemm_core64s(A0, B0, acc, wm, wn, lane);
    __syncthreads();                               // drain prefetch + WAR-protect A0/B0
    if (k + 2 < nk) STAGE(A0, B0, (k + 2) * 64)
    gemm_core64s(A1, B1, acc, wm, wn, lane);
    __syncthreads();
  }
#undef STAGE

  // ---- epilogue: stage C (64x128 bf16) in LDS, then full-line stores ----
  unsigned short* Ct = lds;            // 64 x LDC = 8704 shorts <= 24576
  const int rbc = lane & 15, rg = (lane >> 4) * 4;
#pragma unroll
  for (int i = 0; i < 2; ++i)
#pragma unroll
    for (int j = 0; j < 4; ++j) {
      int col = wn * 64 + j * 16 + rbc;            // 0..127 local
      float bv = bet[n0 + col];
#pragma unroll
      for (int reg = 0; reg < 4; ++reg) {
        int row = wm * 32 + i * 16 + rg + reg;     // 0..63 local
        Ct[row * LDC + col] = f2b(acc[i][j][reg] + bv);
      }
    }
  __syncthreads();
  const bool wdst = (r == m);
  const bool wout = (r < m) || (s == L_prev + m);  // outs[li] = h(li,li)
  unsigned short* d1 = dst  + (size_t)s * NH + (size_t)nb0 * HD + n0;
  unsigned short* d2 = outs + (size_t)s * NH + (size_t)nb0 * HD + n0;
  const int lrow = tid >> 4, lcol = (tid & 15) * 8;  // 16 thr x 16B = 256B/row
#pragma unroll
  for (int sweep = 0; sweep < 4; ++sweep) {
    int row = sweep * 16 + lrow;
    uint4 v = *(const uint4*)&Ct[row * LDC + lcol];
    if (wdst) *(uint4*)(d1 + (size_t)row * HD + lcol) = v;
    if (wout) *(uint4*)(d2 + (size_t)row * HD + lcol) = v;
  }
}

// ---- phase 3 (TEMPLATE): Y = outs_flat @ W_out^T + b_out (fp32 out). ----
__global__ __launch_bounds__(256) void k_gemm_out(const unsigned short* __restrict__ outs,
                                                  const unsigned short* __restrict__ Wb,
                                                  const float* __restrict__ bias,
                                                  float* __restrict__ Y) {
  __shared__ unsigned short lds[24576];
  unsigned short* const A0 = lds;
  unsigned short* const A1 = lds + 4096;
  unsigned short* const B0 = lds + 8192;
  unsigned short* const B1 = lds + 16384;
  const int tid = threadIdx.x;
  const int mtile = blockIdx.x >> 2, ntile = blockIdx.x & 3;
  const int m0 = mtile * 64, n0 = ntile * 128;
  const int lane = tid & 63, wave = tid >> 6, wm = wave >> 1, wn = wave & 1;
  const int rr_ = tid >> 3;
  const int kcs = (((tid & 7) ^ ((tid >> 3) & 7))) * 8;
  const unsigned short* abase = outs + (size_t)m0 * 512;
  const unsigned short* Bp = Wb + (size_t)n0 * 512;

  floatx4 acc[2][4] = {};

#define STAGE_O(Ab, Bb, kcol)                                                        \
  { unsigned short* lA = (Ab) + (tid >> 6) * 512;                                    \
    unsigned short* lB = (Bb) + (tid >> 6) * 512;                                    \
    gl_lds16(abase + (size_t)rr_ * 512 + (kcol) + kcs, lA);                          \
    gl_lds16(abase + (size_t)(rr_ + 32) * 512 + (kcol) + kcs, lA + 2048);            \
    gl_lds16(Bp + (size_t)rr_ * 512 + (kcol) + kcs, lB);                             \
    gl_lds16(Bp + (size_t)(rr_ + 32) * 512 + (kcol) + kcs, lB + 2048);               \
    gl_lds16(Bp + (size_t)(rr_ + 64) * 512 + (kcol) + kcs, lB + 4096);               \
    gl_lds16(Bp + (size_t)(rr_ + 96) * 512 + (kcol) + kcs, lB + 6144); }

  STAGE_O(A0, B0, 0)
  __syncthreads();
  for (int k = 0; k < 8; k += 2) {
    if (k + 1 < 8) STAGE_O(A1, B1, (k + 1) * 64)
    gemm_core64s(A0, B0, acc, wm, wn, lane);
    __syncthreads();
    if (k + 2 < 8) STAGE_O(A0, B0, (k + 2) * 64)
    gemm_core64s(A1, B1, acc, wm, wn, lane);
    __syncthreads();
  }
#undef STAGE_O

  // ---- epilogue: stage C (64x128 f32) in LDS, then full-line stores ----
  float* Ctf = (float*)lds;            // 64 x LDCF x 4B = 33792 B <= 49152
  const int rbc = lane & 15, rg = (lane >> 4) * 4;
#pragma unroll
  for (int i = 0; i < 2; ++i)
#pragma unroll
    for (int j = 0; j < 4; ++j) {
      int col = wn * 64 + j * 16 + rbc;
      float bv = bias[n0 + col];
#pragma unroll
      for (int reg = 0; reg < 4; ++reg) {
        int row = wm * 32 + i * 16 + rg + reg;
        Ctf[row * LDCF + col] = acc[i][j][reg] + bv;
      }
    }
  __syncthreads();
  const int lrow = tid >> 5, lc = (tid & 31) * 4;   // 32 thr x 16B = 512B/row
#pragma unroll
  for (int sweep = 0; sweep < 8; ++sweep) {
    int row = sweep * 8 + lrow;
    uint4 v = *(const uint4*)&Ctf[row * LDCF + lc];
    *(uint4*)&Y[(size_t)(m0 + row) * 512 + n0 + lc] = v;
  }
}

// ---- loss: per n, column-softmax over 64 consecutive Y rows, dot with emb ----
__global__ __launch_bounds__(256) void k_loss(const float* __restrict__ Y,
                                              const float* __restrict__ table,
                                              const int* __restrict__ labels,
                                              float* __restrict__ partials) {
  int n = blockIdx.x, tid = threadIdx.x;
  float total = 0.f;
#pragma unroll
  for (int e2 = 0; e2 < 2; ++e2) {
    int e = e2 * 256 + tid;
    float mx = -1e30f;
    for (int l = 0; l < 64; ++l)
      mx = fmaxf(mx, Y[(size_t)(n * 64 + l) * 512 + e]);
    float se = 0.f;
    for (int l = 0; l < 64; ++l)
      se += expf(Y[(size_t)(n * 64 + l) * 512 + e] - mx);
    float lse = mx + logf(se);
    for (int l = 0; l < 64; ++l) {
      float embv = table[(size_t)labels[n * 64 + l] * ED + e];
      total += embv * (Y[(size_t)(n * 64 + l) * 512 + e] - lse);
    }
  }
  __shared__ float red[256];
  red[tid] = total;
  __syncthreads();
  for (int s2 = 128; s2 > 0; s2 >>= 1) {
    if (tid < s2) red[tid] += red[tid + s2];
    __syncthreads();
  }
  if (tid == 0) partials[n] = red[0];
}

__global__ void k_final(const float* __restrict__ partials, float* __restrict__ out) {
  if (threadIdx.x == 0) {
    double s = 0.0;
    for (int i = 0; i < 128; ++i) s += (double)partials[i];
    out[0] = (float)(-s / 65536.0);
  }
}

extern "C" void kernel_launch(void* const* d_in, const int* in_sizes, int n_in,
                              void* d_out, int out_size, void* d_ws, size_t ws_size,
                              hipStream_t stream) {
  const int*   labels = (const int*)d_in[0];
  const float* table  = (const float*)d_in[1];
  const float* W_in   = (const float*)d_in[2];
  const float* b_in   = (const float*)d_in[3];
  const float* W_sani = (const float*)d_in[4];
  const float* b_sani = (const float*)d_in[5];
  const float* W_out  = (const float*)d_in[6];
  const float* b_out  = (const float*)d_in[7];

  char* ws = (char*)d_ws;
  unsigned short* Win_b  = (unsigned short*)(ws + OFF_WIN);
  unsigned short* Wout_b = (unsigned short*)(ws + OFF_WOUT);
  unsigned short* xt     = (unsigned short*)(ws + OFF_XT);
  unsigned short* lvl0   = (unsigned short*)(ws + OFF_LVL0);
  unsigned short* lvl1   = (unsigned short*)(ws + OFF_LVL1);
  unsigned short* outs   = (unsigned short*)(ws + OFF_OUTS);
  unsigned short* PhiA   = (unsigned short*)(ws + OFF_PHA);
  unsigned short* PloA   = (unsigned short*)(ws + OFF_PLA);
  unsigned short* PhiB   = (unsigned short*)(ws + OFF_PHB);
  unsigned short* PloB   = (unsigned short*)(ws + OFF_PLB);
  unsigned short* Bcat   = (unsigned short*)(ws + OFF_BCAT);
  float*          beta   = (float*)(ws + OFF_BETA);
  float*          parts  = (float*)(ws + OFF_PART);
  unsigned short* WsLo   = (unsigned short*)(ws + OFF_WSLO);
  float*          Y      = (float*)(ws + OFF_Y);

  // Launch 1: cvtw (1024) + beta_1 copy (1) + trW (128)
  k_phase1<<<1153, 256, 0, stream>>>(W_in, W_sani, W_out, Win_b, Bcat, WsLo, Wout_b,
                                     b_sani, beta, PhiA, PloA);

  // Launch 2: coef1 (96) + bias beta_2 (128) + emb GEMM (512, independent, overlaps)
  k_coef<<< 96 + 128 + 512, 256, 0, stream>>>(PhiA, PloA, PhiB, PloB, Bcat, WsLo, 1,
                                        Bcat + 524288, W_sani, b_sani,
                                        beta, beta + 512, 512,
                                        table, labels, Win_b, b_in, xt, outs);
  k_coef<<<128 + 128, 256, 0, stream>>>(PhiB, PloB, PhiA, PloA, Bcat, WsLo, 2,
                                        Bcat + 1310720, W_sani, b_sani,
                                        beta + 512, beta + 1024, 0,
                                        table, labels, Win_b, b_in, xt, outs);
  k_coef<<<160 + 128, 256, 0, stream>>>(PhiA, PloA, PhiB, PloB, Bcat, WsLo, 3,
                                        Bcat + 2359296, W_sani, b_sani,
                                        beta + 1024, beta + 1536, 0,
                                        table, labels, Win_b, b_in, xt, outs);

  // 16 multi-level steps (15 x m=4, 1 x m=3)
  const unsigned short* srcp = xt;
  for (int j = 1; j <= 16; ++j) {
    int L_prev = 4 * (j - 1);
    int m = (j == 16) ? 3 : 4;
    int nmain = 64 - (L_prev + m);
    int g = (nmain + 3) >> 2;          // slabs per s-group (4 s-groups)
    unsigned short* dstp = ((j - 1) & 1) ? lvl1 : lvl0;
    k_step<<<32 * g + (m - 1) * 8, 256, 0, stream>>>(srcp, dstp, outs, Bcat, beta,
                                                     L_prev, m, nmain, g);
    srcp = dstp;
  }

  k_gemm_out<<<512, 256, 0, stream>>>(outs, Wout_b, b_out, Y);
  k_loss<<<128, 256, 0, stream>>>(Y, table, labels, parts);
  k_final<<<1, 64, 0, stream>>>(parts, (float*)d_out);
}